// Round 4
// baseline (1856.453 us; speedup 1.0000x reference)
//
#include <hip/hip_runtime.h>
#include <hip/hip_bf16.h>

// ---------------------------------------------------------------------------
// SelfAttention2d: N=8, Cin=256, H=W=32, Cout=512, K=3, DK=DV=128, NH=8
// dkh=dvh=16, HW=1024. Inputs fp32, OUTPUT fp32 (reference returns float32!),
// compute fp32.
//
// Memory plan:
//   ws   : transposed weights (3.8 MiB) + AR fp32 (4 MiB) = 8,192,000 B
//   d_out: 16 MiB fp32; first 12 MiB double as fp32 Q/K/V scratch, dead by
//          the time conv3x3/attn_out overwrite them (in-order stream).
// Order: prep -> kqv(QKV into d_out) -> attn(reads QKV, AR into ws)
//        -> conv3x3(out ch 0..383) -> attn_out(reads AR, out ch 384..511)
// ---------------------------------------------------------------------------

// ---- ws layout (float offsets) ----
#define OFF_WOUT 0           // [ci][t9][co384]   884736
#define OFF_WKQV 884736      // [ci][co384]       98304
#define OFF_WATT 983040      // [ci][co128]       16384
#define OFF_AR   999424      // [b][128][1024] fp32 raw-reshaped attn  1048576
// end 2048000 floats = 8,192,000 bytes

// ---- d_out scratch layout (float offsets) ----
#define QS_KT 0              // [bh][pos][16] fp32, 1048576 elems each
#define QS_QT 1048576
#define QS_VT 2097152        // end 3145728 < out_size 4194304

// ---------------------------------------------------------------------------
__global__ __launch_bounds__(256) void prep_kernel(
    const float* __restrict__ w_out, const float* __restrict__ w_kqv,
    const float* __restrict__ w_attn, float* __restrict__ ws) {
  int i = blockIdx.x * 256 + threadIdx.x;
  if (i < 884736) {                       // w_out [co][ci][3][3] -> [ci][t][co]
    int co = i / 2304, r = i % 2304;
    int ci = r / 9, t = r % 9;
    ws[OFF_WOUT + (ci * 9 + t) * 384 + co] = w_out[i];
  } else if (i < 983040) {                // w_kqv [co][ci] -> [ci][co]
    int j = i - 884736; int co = j >> 8, ci = j & 255;
    ws[OFF_WKQV + ci * 384 + co] = w_kqv[j];
  } else if (i < 999424) {                // w_attn [co][ci] -> [ci][co]
    int j = i - 983040; int co = j >> 7, ci = j & 127;
    ws[OFF_WATT + ci * 128 + co] = w_attn[j];
  }
}

// ---------------------------------------------------------------------------
// kqv 1x1 conv: 1 thread = 1 pos, co_tile=48. x reads coalesced (tid = pos);
// weights wave-uniform -> s_load. Writes fp32 q/k/v into d_out scratch
// ([bh][pos][16], q pre-scaled by DKH^-0.5 = 0.25).
__global__ __launch_bounds__(256) void kqv_kernel(
    const float* __restrict__ x, const float* __restrict__ wkqv,
    const float* __restrict__ bkqv, float* __restrict__ qsf) {
  int tid = threadIdx.x;
  int pc = blockIdx.x, cc = blockIdx.y, b = blockIdx.z;
  int pos = pc * 256 + tid;
  int co0 = cc * 48;
  float acc[48];
#pragma unroll
  for (int j = 0; j < 48; ++j) acc[j] = bkqv[co0 + j];

  const float* xb = x + (size_t)b * 256 * 1024 + pos;
#pragma unroll 4
  for (int ci = 0; ci < 256; ++ci) {
    float xv = xb[(size_t)ci * 1024];
    const float* wr = wkqv + (size_t)ci * 384 + co0;
#pragma unroll
    for (int j = 0; j < 48; ++j) acc[j] += xv * wr[j];
  }
  // scatter: co0 % 16 == 0, so each j-quad targets one (h, d-quad)
#pragma unroll
  for (int j = 0; j < 48; j += 4) {
    int c = co0 + j;
    float s = 1.0f;
    float* dst;
    int cr;
    if (c < 128)      { dst = qsf + QS_KT; cr = c; }
    else if (c < 256) { dst = qsf + QS_QT; cr = c - 128; s = 0.25f; }
    else              { dst = qsf + QS_VT; cr = c - 256; }
    int h = cr >> 4, d = cr & 15;
    float4 v4;
    v4.x = acc[j] * s;     v4.y = acc[j + 1] * s;
    v4.z = acc[j + 2] * s; v4.w = acc[j + 3] * s;
    *(float4*)(dst + ((size_t)(b * 8 + h) * 1024 + pos) * 16 + d) = v4;
  }
}

// ---------------------------------------------------------------------------
// attention: block = 128 threads (1 query row each), grid (mc 8, h 8, b 8).
// Dynamic LDS: pwph[128][127] (private per-thread row, no barrier needed).
// logits[m][n] = q_m.k_n + pw[nx-mx+31] + ph[ny-my+31]; softmax with fixed
// shift 12 (mathematically exact; logits bounded ~|9|, no under/overflow).
__global__ __launch_bounds__(128) void attn_kernel(
    const float* __restrict__ qsf, const float* __restrict__ krw,
    const float* __restrict__ krh, float* __restrict__ ar) {
  extern __shared__ float pwph[];
  int tid = threadIdx.x;
  int mc = blockIdx.x, h = blockIdx.y, b = blockIdx.z;
  int m = mc * 128 + tid;
  int bh = b * 8 + h;

  float q[16];
  {
    const float4* q4 = (const float4*)(qsf + QS_QT + ((size_t)bh * 1024 + m) * 16);
#pragma unroll
    for (int i = 0; i < 4; ++i) {
      float4 t = q4[i];
      q[4 * i] = t.x; q[4 * i + 1] = t.y; q[4 * i + 2] = t.z; q[4 * i + 3] = t.w;
    }
  }

  float* myrow = pwph + tid * 127;     // [0,63): pw   [63,126): ph
  for (int c = 0; c < 63; ++c) {
    const float* wr = krw + c * 16;
    const float* hr = krh + c * 16;
    float sw = 0.f, sh = 0.f;
#pragma unroll
    for (int d = 0; d < 16; ++d) { sw += q[d] * wr[d]; sh += q[d] * hr[d]; }
    myrow[c] = sw;
    myrow[63 + c] = sh;
  }

  int my = m >> 5, mx = m & 31;
  float acc[16];
#pragma unroll
  for (int d = 0; d < 16; ++d) acc[d] = 0.f;
  float ssum = 0.f;
  const float* kbase = qsf + QS_KT + (size_t)bh * 16384;
  const float* vbase = qsf + QS_VT + (size_t)bh * 16384;

  for (int ny = 0; ny < 32; ++ny) {
    float ph = myrow[63 + ny - my + 31];
#pragma unroll 4
    for (int nx = 0; nx < 32; ++nx) {
      int n = ny * 32 + nx;
      const float* kr = kbase + (size_t)n * 16;   // wave-uniform -> s_load
      const float* vr = vbase + (size_t)n * 16;
      float qk = 0.f;
#pragma unroll
      for (int d = 0; d < 16; ++d) qk += q[d] * kr[d];
      float logit = qk + ph + myrow[nx - mx + 31];
      float p = __expf(logit - 12.0f);
      ssum += p;
#pragma unroll
      for (int d = 0; d < 16; ++d) acc[d] += p * vr[d];
    }
  }
  float inv = 1.0f / ssum;
  // raw-reshape layout: flat = h*16384 + m*16 + d  (the (N,DV,H,W) view)
  float* orow = ar + (size_t)b * 131072 + (size_t)h * 16384 + (size_t)m * 16;
#pragma unroll
  for (int i = 0; i < 4; ++i) {
    float4 t;
    t.x = acc[4 * i] * inv;     t.y = acc[4 * i + 1] * inv;
    t.z = acc[4 * i + 2] * inv; t.w = acc[4 * i + 3] * inv;
    ((float4*)orow)[i] = t;
  }
}

// ---------------------------------------------------------------------------
// 3x3 conv, pad 1: out channels [0,384). block=256 (8 rows x 32 cols),
// co_tile=48, ci chunks of 32 staged in LDS (10 rows incl. halo, fp32).
__global__ __launch_bounds__(256) void conv3x3_kernel(
    const float* __restrict__ x, const float* __restrict__ wt,
    const float* __restrict__ bo, float* __restrict__ out) {
  __shared__ float xs[32 * 320];
  int tid = threadIdx.x;
  int pc = blockIdx.x, cc = blockIdx.y, b = blockIdx.z;
  int co0 = cc * 48;
  int col = tid & 31, r = tid >> 5;     // r in [0,8)
  int y0 = pc * 8;

  float acc[48];
#pragma unroll
  for (int j = 0; j < 48; ++j) acc[j] = bo[co0 + j];

  for (int cb = 0; cb < 8; ++cb) {
    int ci0 = cb * 32;
    __syncthreads();
    for (int p = 0; p < 40; ++p) {      // stage 320 (ci,row) pairs
      int pair = p * 8 + r;
      int ci = pair / 10, row = pair % 10;
      int ys = y0 - 1 + row;
      float v = 0.f;
      if (ys >= 0 && ys < 32)
        v = x[(size_t)(b * 256 + ci0 + ci) * 1024 + ys * 32 + col];
      xs[ci * 320 + row * 32 + col] = v;
    }
    __syncthreads();
    for (int ci = 0; ci < 32; ++ci) {
#pragma unroll
      for (int ky = 0; ky < 3; ++ky) {
        int base = ci * 320 + (r + ky) * 32 + col;
        float xm = (col > 0)  ? xs[base - 1] : 0.f;
        float xc = xs[base];
        float xp = (col < 31) ? xs[base + 1] : 0.f;
        const float* w0 = wt + ((size_t)(ci0 + ci) * 9 + ky * 3) * 384 + co0;
        const float* w1 = w0 + 384;
        const float* w2 = w1 + 384;
#pragma unroll
        for (int j = 0; j < 48; ++j)
          acc[j] += xm * w0[j] + xc * w1[j] + xp * w2[j];
      }
    }
  }
  int pos = y0 * 32 + tid;
  size_t obase = ((size_t)b * 512 + co0) * 1024 + pos;
#pragma unroll
  for (int j = 0; j < 48; ++j)
    out[obase + (size_t)j * 1024] = acc[j];
}

// ---------------------------------------------------------------------------
// final 1x1 conv on raw-reshaped attn -> out channels [384,512)
__global__ __launch_bounds__(256) void attn_out_kernel(
    const float* __restrict__ ar, const float* __restrict__ wt,
    const float* __restrict__ ba, float* __restrict__ out) {
  int tid = threadIdx.x;
  int pc = blockIdx.x, cc = blockIdx.y, b = blockIdx.z;
  int pos = pc * 256 + tid;
  int co0 = cc * 32;
  float acc[32];
#pragma unroll
  for (int j = 0; j < 32; ++j) acc[j] = ba[co0 + j];

  const float* arb = ar + (size_t)b * 131072 + pos;
#pragma unroll 4
  for (int ci = 0; ci < 128; ++ci) {
    float xv = arb[(size_t)ci * 1024];
    const float* wr = wt + (size_t)ci * 128 + co0;
#pragma unroll
    for (int j = 0; j < 32; ++j) acc[j] += xv * wr[j];
  }
  size_t obase = ((size_t)b * 512 + 384 + co0) * 1024 + pos;
#pragma unroll
  for (int j = 0; j < 32; ++j)
    out[obase + (size_t)j * 1024] = acc[j];
}

// ---------------------------------------------------------------------------
extern "C" void kernel_launch(void* const* d_in, const int* in_sizes, int n_in,
                              void* d_out, int out_size, void* d_ws, size_t ws_size,
                              hipStream_t stream) {
  const float* x      = (const float*)d_in[0];
  const float* b_out  = (const float*)d_in[2];
  const float* b_kqv  = (const float*)d_in[4];
  const float* b_attn = (const float*)d_in[6];
  const float* krw    = (const float*)d_in[7];
  const float* krh    = (const float*)d_in[8];
  float* ws  = (float*)d_ws;
  float* out = (float*)d_out;          // reference output dtype is float32

  prep_kernel<<<3904, 256, 0, stream>>>(
      (const float*)d_in[1], (const float*)d_in[3], (const float*)d_in[5], ws);
  kqv_kernel<<<dim3(4, 8, 8), 256, 0, stream>>>(
      x, ws + OFF_WKQV, b_kqv, out);
  attn_kernel<<<dim3(8, 8, 8), 128, 128 * 127 * 4, stream>>>(
      out, krw, krh, ws + OFF_AR);
  conv3x3_kernel<<<dim3(4, 8, 8), 256, 0, stream>>>(
      x, ws + OFF_WOUT, b_out, out);
  attn_out_kernel<<<dim3(4, 4, 8), 256, 0, stream>>>(
      ws + OFF_AR, ws + OFF_WATT, b_attn, out);
}

// Round 5
// 746.060 us; speedup vs baseline: 2.4883x; 2.4883x over previous
//
#include <hip/hip_runtime.h>
#include <hip/hip_bf16.h>

// ---------------------------------------------------------------------------
// SelfAttention2d: N=8, Cin=256, H=W=32, Cout=512, K=3, DK=DV=128, NH=8
// dkh=dvh=16, HW=1024. Inputs fp32, OUTPUT fp32, compute fp32 (conv in bf16
// MFMA, fp32 accumulate).
//
// ws layout (bytes; total 8,093,696 <= proven-safe 8,192,000):
//   [0        ) w_bf  bf16 [t9][co384][ci256]   1,769,472
//   [1,769,472) watt  bf16 [ci128][co128]          32,768
//   [1,802,240) xT    bf16 [b][pos1024][ci256]  4,194,304
//   [5,996,544) AR    bf16 [b][128][1024]       2,097,152
//      (wkqv_t fp32 [ci][co384] 393,216 B overlaps AR start; dead before attn)
// d_out (16.8 MB fp32) doubles as fp32 QKV scratch [0,12.6MB) until attn done.
// Order: prep -> xt -> kqv -> attn -> bias_init -> conv_mfma(atomic) -> attn_out
// ---------------------------------------------------------------------------

typedef short v8s __attribute__((ext_vector_type(8)));
typedef float v4f __attribute__((ext_vector_type(4)));

// ws offsets (element units)
#define WBF_US   0u          // ushort idx
#define WATT_US  884736u
#define XT_US    901120u
#define AR_US    2998272u
#define WKQVT_F  1499136u    // float idx (byte 5,996,544 == AR start)

// d_out scratch (float offsets)
#define QS_KT 0
#define QS_QT 1048576
#define QS_VT 2097152

__device__ __forceinline__ unsigned short f2bs(float f) {
  __hip_bfloat16 h = __float2bfloat16(f);
  return *reinterpret_cast<unsigned short*>(&h);
}
__device__ __forceinline__ float bs2f(unsigned short u) {
  union { float f; unsigned i; } c; c.i = ((unsigned)u) << 16; return c.f;
}

// ---------------------------------------------------------------------------
// prep: w_out -> w_bf bf16 [t][co][ci]; w_attn -> watt bf16 [ci][co];
//       w_kqv -> wkqv_t fp32 [ci][co].
__global__ __launch_bounds__(256) void prep_kernel(
    const float* __restrict__ w_out, const float* __restrict__ w_kqv,
    const float* __restrict__ w_attn, unsigned short* __restrict__ ws_us,
    float* __restrict__ ws_f) {
  int i = blockIdx.x * 256 + threadIdx.x;
  if (i < 884736) {                     // w_bf[(t*384+co)*256+ci] = w_out[co][ci][t]
    int ci = i & 255, r = i >> 8;
    int co = r % 384, t = r / 384;
    ws_us[WBF_US + i] = f2bs(w_out[(size_t)co * 2304 + ci * 9 + t]);
  } else if (i < 901120) {              // watt[ci*128+co] = w_attn[co*128+ci]
    int j = i - 884736; int ci = j >> 7, co = j & 127;
    ws_us[WATT_US + j] = f2bs(w_attn[co * 128 + ci]);
  } else if (i < 999424) {              // wkqv_t[ci*384+co] = w_kqv[co*256+ci]
    int j = i - 901120; int ci = j / 384, co = j % 384;
    ws_f[WKQVT_F + j] = w_kqv[co * 256 + ci];
  }
}

// ---------------------------------------------------------------------------
// xT: [b][ci][pos] fp32 -> [b][pos][ci] bf16 via LDS tile (64x64, pad 65).
__global__ __launch_bounds__(256) void xt_kernel(
    const float* __restrict__ x, unsigned short* __restrict__ xt) {
  __shared__ float t[64][65];
  int tid = threadIdx.x; int pl = tid & 63, cg = tid >> 6;
  int pos0 = blockIdx.x * 64, ci0 = blockIdx.y * 64, b = blockIdx.z;
  const float* xb = x + ((size_t)(b * 256 + ci0)) * 1024 + pos0;
#pragma unroll
  for (int i = 0; i < 16; ++i) {
    int ci_l = cg * 16 + i;
    t[ci_l][pl] = xb[(size_t)ci_l * 1024 + pl];
  }
  __syncthreads();
#pragma unroll
  for (int i = 0; i < 16; ++i) {
    int pos_l = cg * 16 + i;
    xt[((size_t)(b * 1024 + pos0 + pos_l)) * 256 + ci0 + pl] = f2bs(t[pl][pos_l]);
  }
}

// ---------------------------------------------------------------------------
// kqv 1x1 conv (fp32): 1 thread = 1 pos, co_tile=48; writes fp32 QKV into
// d_out scratch [bh][pos][16] (q pre-scaled 0.25).
__global__ __launch_bounds__(256) void kqv_kernel(
    const float* __restrict__ x, const float* __restrict__ wkqv,
    const float* __restrict__ bkqv, float* __restrict__ qsf) {
  int tid = threadIdx.x;
  int pc = blockIdx.x, cc = blockIdx.y, b = blockIdx.z;
  int pos = pc * 256 + tid;
  int co0 = cc * 48;
  float acc[48];
#pragma unroll
  for (int j = 0; j < 48; ++j) acc[j] = bkqv[co0 + j];

  const float* xb = x + (size_t)b * 256 * 1024 + pos;
#pragma unroll 4
  for (int ci = 0; ci < 256; ++ci) {
    float xv = xb[(size_t)ci * 1024];
    const float* wr = wkqv + (size_t)ci * 384 + co0;
#pragma unroll
    for (int j = 0; j < 48; ++j) acc[j] += xv * wr[j];
  }
#pragma unroll
  for (int j = 0; j < 48; j += 4) {
    int c = co0 + j;
    float s = 1.0f;
    float* dst;
    int cr;
    if (c < 128)      { dst = qsf + QS_KT; cr = c; }
    else if (c < 256) { dst = qsf + QS_QT; cr = c - 128; s = 0.25f; }
    else              { dst = qsf + QS_VT; cr = c - 256; }
    int h = cr >> 4, d = cr & 15;
    float4 v4;
    v4.x = acc[j] * s;     v4.y = acc[j + 1] * s;
    v4.z = acc[j + 2] * s; v4.w = acc[j + 3] * s;
    *(float4*)(dst + ((size_t)(b * 8 + h) * 1024 + pos) * 16 + d) = v4;
  }
}

// ---------------------------------------------------------------------------
// attention: 1 thread = 1 query row; grid (8,8,8) x 128 thr.
__global__ __launch_bounds__(128) void attn_kernel(
    const float* __restrict__ qsf, const float* __restrict__ krw,
    const float* __restrict__ krh, unsigned short* __restrict__ ar) {
  extern __shared__ float pwph[];
  int tid = threadIdx.x;
  int mc = blockIdx.x, h = blockIdx.y, b = blockIdx.z;
  int m = mc * 128 + tid;
  int bh = b * 8 + h;

  float q[16];
  {
    const float4* q4 = (const float4*)(qsf + QS_QT + ((size_t)bh * 1024 + m) * 16);
#pragma unroll
    for (int i = 0; i < 4; ++i) {
      float4 t = q4[i];
      q[4 * i] = t.x; q[4 * i + 1] = t.y; q[4 * i + 2] = t.z; q[4 * i + 3] = t.w;
    }
  }

  float* myrow = pwph + tid * 127;     // [0,63): pw   [63,126): ph
  for (int c = 0; c < 63; ++c) {
    const float* wr = krw + c * 16;
    const float* hr = krh + c * 16;
    float sw = 0.f, sh = 0.f;
#pragma unroll
    for (int d = 0; d < 16; ++d) { sw += q[d] * wr[d]; sh += q[d] * hr[d]; }
    myrow[c] = sw;
    myrow[63 + c] = sh;
  }

  int my = m >> 5, mx = m & 31;
  float acc[16];
#pragma unroll
  for (int d = 0; d < 16; ++d) acc[d] = 0.f;
  float ssum = 0.f;
  const float* kbase = qsf + QS_KT + (size_t)bh * 16384;
  const float* vbase = qsf + QS_VT + (size_t)bh * 16384;

  for (int ny = 0; ny < 32; ++ny) {
    float ph = myrow[63 + ny - my + 31];
#pragma unroll 4
    for (int nx = 0; nx < 32; ++nx) {
      int n = ny * 32 + nx;
      const float* kr = kbase + (size_t)n * 16;   // wave-uniform -> s_load
      const float* vr = vbase + (size_t)n * 16;
      float qk = 0.f;
#pragma unroll
      for (int d = 0; d < 16; ++d) qk += q[d] * kr[d];
      float logit = qk + ph + myrow[nx - mx + 31];
      float p = __expf(logit - 12.0f);
      ssum += p;
#pragma unroll
      for (int d = 0; d < 16; ++d) acc[d] += p * vr[d];
    }
  }
  float inv = 1.0f / ssum;
  unsigned short* orow = ar + (size_t)b * 131072 + (size_t)h * 16384 + (size_t)m * 16;
  unsigned uv[8];
#pragma unroll
  for (int i = 0; i < 8; ++i)
    uv[i] = (unsigned)f2bs(acc[2 * i] * inv) |
            ((unsigned)f2bs(acc[2 * i + 1] * inv) << 16);
  uint4 w0 = {uv[0], uv[1], uv[2], uv[3]};
  uint4 w1 = {uv[4], uv[5], uv[6], uv[7]};
  ((uint4*)orow)[0] = w0;
  ((uint4*)orow)[1] = w1;
}

// ---------------------------------------------------------------------------
// bias init for out channels [0,384): out[b][co][pos] = bias[co]
__global__ __launch_bounds__(256) void bias_init_kernel(
    const float* __restrict__ bo, float* __restrict__ out) {
  int i = blockIdx.x * 256 + threadIdx.x;       // 3,145,728 total
  int pos = i & 1023; int r = i >> 10;          // r = b*384+co
  int co = r % 384, b = r / 384;
  out[(((size_t)(b * 512 + co)) << 10) | pos] = bo[co];
}

// ---------------------------------------------------------------------------
// conv3x3 via MFMA: 9 shifted 1x1 GEMMs. 1 wave/block, tile 64 pos x 64 co,
// K-split by ky (grid.z = ky*8+b) -> 2304 waves, partials via atomicAdd.
// A-frags from xT[b][pos'][ci] (16B/lane), B-frags from w_bf[t][co][ci].
__global__ __launch_bounds__(64) void conv_mfma_kernel(
    const unsigned short* __restrict__ xt,
    const unsigned short* __restrict__ wbf, float* __restrict__ out) {
  int lane = threadIdx.x;
  int pt = blockIdx.x, ct = blockIdx.y, z = blockIdx.z;
  int b = z & 7, ky = z >> 3;
  int pos0 = pt * 64, co0 = ct * 64;
  int il = lane & 15, q = lane >> 4;
  int row0 = pos0 >> 5;                 // 2 output rows per block: row0,row0+1

  v4f acc[4][4];
#pragma unroll
  for (int mt = 0; mt < 4; ++mt)
#pragma unroll
    for (int nt = 0; nt < 4; ++nt) acc[mt][nt] = (v4f){0.f, 0.f, 0.f, 0.f};

  const unsigned short* abase[4];
  bool rok[4];
#pragma unroll
  for (int mt = 0; mt < 4; ++mt) {
    int rowp = row0 + (mt >> 1) + ky - 1;       // source row for this mt
    rok[mt] = ((unsigned)rowp) < 32u;
    int colb = (mt & 1) * 16 + il - 1;          // source col at kx=0
    long off = ((long)(b * 1024) + (long)rowp * 32 + colb) * 256 + q * 8;
    abase[mt] = xt + off;                       // guarded when !rok / edge
  }
  const unsigned short* bbase = wbf + ((size_t)(ky * 3) * 384 + co0 + il) * 256 + q * 8;

  const v8s z8 = {0, 0, 0, 0, 0, 0, 0, 0};
  for (int kc = 0; kc < 8; ++kc) {
#pragma unroll
    for (int kx = 0; kx < 3; ++kx) {
      v8s bfrag[4];
#pragma unroll
      for (int nt = 0; nt < 4; ++nt)
        bfrag[nt] = *(const v8s*)(bbase + (size_t)kx * 98304 + nt * 4096 + kc * 32);
      v8s afrag[4];
#pragma unroll
      for (int mt = 0; mt < 4; ++mt) {
        bool ok = rok[mt];
        if (kx == 0) ok = ok && !((il == 0) && ((mt & 1) == 0));   // col' = -1
        if (kx == 2) ok = ok && !((il == 15) && ((mt & 1) == 1));  // col' = 32
        const v8s* p = (const v8s*)(abase[mt] + kx * 256 + kc * 32);
        p = ok ? p : (const v8s*)xt;            // safe dummy address
        v8s a = *p;
        afrag[mt] = ok ? a : z8;
      }
#pragma unroll
      for (int mt = 0; mt < 4; ++mt)
#pragma unroll
        for (int nt = 0; nt < 4; ++nt)
          acc[mt][nt] = __builtin_amdgcn_mfma_f32_16x16x32_bf16(
              afrag[mt], bfrag[nt], acc[mt][nt], 0, 0, 0);
    }
  }
  // D layout: col(co) = lane&15, row(pos) = q*4 + reg
#pragma unroll
  for (int mt = 0; mt < 4; ++mt) {
    int posb = pos0 + mt * 16 + q * 4;
#pragma unroll
    for (int nt = 0; nt < 4; ++nt) {
      int co = co0 + nt * 16 + il;
      float* o = out + ((size_t)(b * 512 + co)) * 1024 + posb;
#pragma unroll
      for (int r = 0; r < 4; ++r) atomicAdd(o + r, acc[mt][nt][r]);
    }
  }
}

// ---------------------------------------------------------------------------
// final 1x1 conv on bf16 AR -> out channels [384,512)
__global__ __launch_bounds__(256) void attn_out_kernel(
    const unsigned short* __restrict__ ar, const unsigned short* __restrict__ watt,
    const float* __restrict__ ba, float* __restrict__ out) {
  int tid = threadIdx.x;
  int pc = blockIdx.x, cc = blockIdx.y, b = blockIdx.z;
  int pos = pc * 256 + tid;
  int co0 = cc * 32;
  float acc[32];
#pragma unroll
  for (int j = 0; j < 32; ++j) acc[j] = ba[co0 + j];

  const unsigned short* arb = ar + (size_t)b * 131072 + pos;
#pragma unroll 4
  for (int ci = 0; ci < 128; ++ci) {
    float xv = bs2f(arb[(size_t)ci * 1024]);
    const unsigned short* wr = watt + (size_t)ci * 128 + co0;
#pragma unroll
    for (int j = 0; j < 32; ++j) acc[j] += xv * bs2f(wr[j]);
  }
  size_t obase = ((size_t)b * 512 + 384 + co0) * 1024 + pos;
#pragma unroll
  for (int j = 0; j < 32; ++j)
    out[obase + (size_t)j * 1024] = acc[j];
}

// ---------------------------------------------------------------------------
extern "C" void kernel_launch(void* const* d_in, const int* in_sizes, int n_in,
                              void* d_out, int out_size, void* d_ws, size_t ws_size,
                              hipStream_t stream) {
  const float* x      = (const float*)d_in[0];
  const float* b_out  = (const float*)d_in[2];
  const float* b_kqv  = (const float*)d_in[4];
  const float* b_attn = (const float*)d_in[6];
  const float* krw    = (const float*)d_in[7];
  const float* krh    = (const float*)d_in[8];
  unsigned short* ws_us = (unsigned short*)d_ws;
  float* ws_f = (float*)d_ws;
  float* out = (float*)d_out;

  prep_kernel<<<3904, 256, 0, stream>>>(
      (const float*)d_in[1], (const float*)d_in[3], (const float*)d_in[5],
      ws_us, ws_f);
  xt_kernel<<<dim3(16, 4, 8), 256, 0, stream>>>(x, ws_us + XT_US);
  kqv_kernel<<<dim3(4, 8, 8), 256, 0, stream>>>(
      x, ws_f + WKQVT_F, b_kqv, out);
  attn_kernel<<<dim3(8, 8, 8), 128, 128 * 127 * 4, stream>>>(
      out, krw, krh, ws_us + AR_US);
  bias_init_kernel<<<12288, 256, 0, stream>>>(b_out, out);
  conv_mfma_kernel<<<dim3(16, 6, 24), 64, 0, stream>>>(
      ws_us + XT_US, ws_us + WBF_US, out);
  attn_out_kernel<<<dim3(4, 4, 8), 256, 0, stream>>>(
      ws_us + AR_US, ws_us + WATT_US, b_attn, out);
}

// Round 6
// 217.665 us; speedup vs baseline: 8.5289x; 3.4276x over previous
//
#include <hip/hip_runtime.h>
#include <hip/hip_bf16.h>

// ---------------------------------------------------------------------------
// SelfAttention2d, fully-MFMA pipeline. Inputs fp32, output fp32.
// Verified-by-round-5 MFMA layouts (16x16x32 bf16):
//   A[m=lane&15][k=(lane>>4)*8+j], B[col=lane&15][k=(lane>>4)*8+j],
//   C[row=(lane>>4)*4+reg][col=lane&15]
// Softmax in exp2 domain: q pre-scaled by 0.25*log2(e); fixed shift folded
// into the PH table (logits bounded ~|11| -> exact, no overflow).
//
// ws (ushort units, total 6,721,536 B <= proven-safe 8,192,000):
//   WBF 0            w_out bf16 [t9][co384][ci256]
//   WKQVB 884736     w_kqv bf16 [co384][ci256]
//   WATTB 983040     w_attn bf16 [co128][ci128]
//   KRWB 999424      krw bf16 [64][16] (row63=0)   KRHB 1000448 same
//   XT 1001472       x bf16 [b][pos][ci]           (alive until conv)
//   ART2 3098624     art slots b=6,7 (262144 us)
// d_out (8388608 us): KS 0 / QS 1048576 / VTS 2097152 (b0-b2 region, dead
//   after attn); ART1 7340032 = b7 ch0..383 region, slots b=0..5 (read by
//   attn_out, overwritten later by conv).
// Order: prep -> xt -> kqv -> attn -> attn_out -> conv
// ---------------------------------------------------------------------------

typedef short v8s __attribute__((ext_vector_type(8)));
typedef float v4f __attribute__((ext_vector_type(4)));

#define WBF_US   0u
#define WKQVB_US 884736u
#define WATTB_US 983040u
#define KRWB_US  999424u
#define KRHB_US  1000448u
#define XT_US    1001472u
#define ART2_US  3098624u

#define KS_US    0u
#define QS_US    1048576u
#define VTS_US   2097152u
#define ART1_US  7340032u

#define QSCALE 0.360673760f   // 0.25 * log2(e)
#define SHIFT2 17.3123405f    // 12 * log2(e)

__device__ __forceinline__ unsigned short f2bs(float f) {
  __hip_bfloat16 h = __float2bfloat16(f);
  return *reinterpret_cast<unsigned short*>(&h);
}

// ---------------------------------------------------------------------------
__global__ __launch_bounds__(256) void prep_kernel(
    const float* __restrict__ w_out, const float* __restrict__ w_kqv,
    const float* __restrict__ w_attn, const float* __restrict__ krw,
    const float* __restrict__ krh, unsigned short* __restrict__ ws) {
  int i = blockIdx.x * 256 + threadIdx.x;
  if (i < 884736) {              // wbf[(t*384+co)*256+ci] = w_out[co][ci][t]
    int ci = i & 255, r = i >> 8;
    int co = r % 384, t = r / 384;
    ws[WBF_US + i] = f2bs(w_out[(size_t)co * 2304 + ci * 9 + t]);
  } else if (i < 983040) {       // direct cast [co][ci]
    int j = i - 884736;
    ws[WKQVB_US + j] = f2bs(w_kqv[j]);
  } else if (i < 999424) {       // direct cast [co][ci]
    int j = i - 983040;
    ws[WATTB_US + j] = f2bs(w_attn[j]);
  } else if (i < 1000448) {      // krw bf16 [64][16], row 63 zero
    int j = i - 999424; int c = j >> 4, d = j & 15;
    ws[KRWB_US + j] = (c < 63) ? f2bs(krw[c * 16 + d]) : (unsigned short)0;
  } else if (i < 1001472) {
    int j = i - 1000448; int c = j >> 4, d = j & 15;
    ws[KRHB_US + j] = (c < 63) ? f2bs(krh[c * 16 + d]) : (unsigned short)0;
  }
}

// ---------------------------------------------------------------------------
// xT: [b][ci][pos] fp32 -> [b][pos][ci] bf16 via LDS 64x64 tile.
__global__ __launch_bounds__(256) void xt_kernel(
    const float* __restrict__ x, unsigned short* __restrict__ xt) {
  __shared__ float t[64][65];
  int tid = threadIdx.x; int pl = tid & 63, cg = tid >> 6;
  int pos0 = blockIdx.x * 64, ci0 = blockIdx.y * 64, b = blockIdx.z;
  const float* xb = x + ((size_t)(b * 256 + ci0)) * 1024 + pos0;
#pragma unroll
  for (int i = 0; i < 16; ++i) {
    int ci_l = cg * 16 + i;
    t[ci_l][pl] = xb[(size_t)ci_l * 1024 + pl];
  }
  __syncthreads();
#pragma unroll
  for (int i = 0; i < 16; ++i) {
    int pos_l = cg * 16 + i;
    xt[((size_t)(b * 1024 + pos0 + pos_l)) * 256 + ci0 + pl] = f2bs(t[pl][pos_l]);
  }
}

// ---------------------------------------------------------------------------
// kqv GEMM: [8192 pos][384 co] = xT[pos][256] * wkqv^T. 64x64 tile per wave.
// Scatters bf16 into KS/QS/VTS in d_out (q scaled by QSCALE after bias).
__global__ __launch_bounds__(64) void kqv_mfma(
    const unsigned short* __restrict__ xt,
    const unsigned short* __restrict__ wkqvb,
    const float* __restrict__ bkqv, unsigned short* __restrict__ dq) {
  int lane = threadIdx.x; int il = lane & 15, q = lane >> 4;
  int m0 = blockIdx.x * 64, co0 = blockIdx.y * 64;
  int b = m0 >> 10, pos0 = m0 & 1023;
  v4f acc[4][4];
#pragma unroll
  for (int mt = 0; mt < 4; ++mt)
#pragma unroll
    for (int nt = 0; nt < 4; ++nt) acc[mt][nt] = (v4f){0.f, 0.f, 0.f, 0.f};

  const unsigned short* ab = xt + (size_t)(m0 + il) * 256 + q * 8;
  const unsigned short* bb = wkqvb + (size_t)(co0 + il) * 256 + q * 8;
  for (int kc = 0; kc < 8; ++kc) {
    v8s af[4], bf[4];
#pragma unroll
    for (int mt = 0; mt < 4; ++mt) af[mt] = *(const v8s*)(ab + mt * 4096 + kc * 32);
#pragma unroll
    for (int nt = 0; nt < 4; ++nt) bf[nt] = *(const v8s*)(bb + nt * 4096 + kc * 32);
#pragma unroll
    for (int mt = 0; mt < 4; ++mt)
#pragma unroll
      for (int nt = 0; nt < 4; ++nt)
        acc[mt][nt] = __builtin_amdgcn_mfma_f32_16x16x32_bf16(
            af[mt], bf[nt], acc[mt][nt], 0, 0, 0);
  }
#pragma unroll
  for (int nt = 0; nt < 4; ++nt) {
    int cob = co0 + nt * 16;
    int co = cob + il;
    float bias = bkqv[co];
    int cls = cob >> 7;                  // 0:k 1:q 2:v (uniform per nt)
    int h = (cob >> 4) & 7;
    size_t bh = (size_t)(b * 8 + h);
#pragma unroll
    for (int mt = 0; mt < 4; ++mt) {
      int pos = pos0 + mt * 16 + q * 4;
      v4f a = acc[mt][nt];
#pragma unroll
      for (int r = 0; r < 4; ++r) {
        float v = a[r] + bias;
        int p = pos + r;
        if (cls == 0)      dq[KS_US + bh * 16384 + p * 16 + il] = f2bs(v);
        else if (cls == 1) dq[QS_US + bh * 16384 + p * 16 + il] = f2bs(v * QSCALE);
        else               dq[VTS_US + bh * 16384 + il * 1024 + p] = f2bs(v);
      }
    }
  }
}

// ---------------------------------------------------------------------------
// MFMA attention. Block 256 = 4 waves; wave owns 16-row m-tile.
// grid (16 mchunk, 64 bh). Per-wave LDS: pw[16r x stride63], ph[x68] (holds
// PH - SHIFT2), plds[16 x 36] for P C->A transpose.
__global__ __launch_bounds__(256) void attn_mfma(
    unsigned short* __restrict__ dq, const unsigned short* __restrict__ krwb,
    const unsigned short* __restrict__ krhb, unsigned short* __restrict__ wsart) {
  __shared__ float lds[4][2688];
  int tid = threadIdx.x; int w = tid >> 6, lane = tid & 63;
  int il = lane & 15, q = lane >> 4;
  int bh = blockIdx.y; int b = bh >> 3, h = bh & 7;
  int m0 = blockIdx.x * 64 + w * 16;
  int my = m0 >> 5, mxb = m0 & 31;
  float* pw = lds[w];
  float* ph = pw + 1024;
  float* pl = ph + 1088;

  const v8s z8 = {0, 0, 0, 0, 0, 0, 0, 0};
  const v4f z4 = {0.f, 0.f, 0.f, 0.f};

  // Q A-frag (K=16, quads 2,3 zero)
  const unsigned short* qrow = dq + QS_US + (size_t)bh * 16384 + (m0 + il) * 16;
  v8s qa = *(const v8s*)(qrow + (q & 1) * 8);
  qa = (q < 2) ? qa : z8;

  // PW / PH tables via MFMA
#pragma unroll
  for (int nt = 0; nt < 4; ++nt) {
    int c = nt * 16 + il;
    v8s bw = *(const v8s*)(krwb + c * 16 + (q & 1) * 8);
    v8s bhh = *(const v8s*)(krhb + c * 16 + (q & 1) * 8);
    bw = (q < 2) ? bw : z8;
    bhh = (q < 2) ? bhh : z8;
    v4f pwc = __builtin_amdgcn_mfma_f32_16x16x32_bf16(qa, bw, z4, 0, 0, 0);
    v4f phc = __builtin_amdgcn_mfma_f32_16x16x32_bf16(qa, bhh, z4, 0, 0, 0);
#pragma unroll
    for (int r = 0; r < 4; ++r) {
      pw[(q * 4 + r) * 63 + c] = pwc[r];
      ph[(q * 4 + r) * 68 + c] = phc[r] - SHIFT2;
    }
  }

  v4f oacc = z4;
  float ssum[4] = {0.f, 0.f, 0.f, 0.f};
  const unsigned short* kbase = dq + KS_US + (size_t)bh * 16384;
  const unsigned short* vbase = dq + VTS_US + (size_t)bh * 16384 + il * 1024;
  int ibase = il + 31 - mxb - q * 4;

  for (int ny = 0; ny < 32; ++ny) {
    int idxh = ny - my + 31;
    float phr[4];
#pragma unroll
    for (int r = 0; r < 4; ++r) phr[r] = ph[(q * 4 + r) * 68 + idxh];
#pragma unroll
    for (int nt2 = 0; nt2 < 2; ++nt2) {
      int nb = ny * 32 + nt2 * 16;
      v8s kb = *(const v8s*)(kbase + (nb + il) * 16 + (q & 1) * 8);
      kb = (q < 2) ? kb : z8;
      v4f s = __builtin_amdgcn_mfma_f32_16x16x32_bf16(qa, kb, z4, 0, 0, 0);
#pragma unroll
      for (int r = 0; r < 4; ++r) {
        float pwv = pw[(q * 4 + r) * 63 + (ibase + nt2 * 16 - r)];
        float t = s[r] + pwv + phr[r];
        float p = exp2f(t);
        ssum[r] += p;
        pl[(q * 4 + r) * 36 + nt2 * 16 + il] = p;
      }
    }
    // PV over this 32-col k-tile
    float4 pa0 = *(const float4*)(pl + il * 36 + q * 8);
    float4 pa1 = *(const float4*)(pl + il * 36 + q * 8 + 4);
    v8s pf;
    pf[0] = (short)f2bs(pa0.x); pf[1] = (short)f2bs(pa0.y);
    pf[2] = (short)f2bs(pa0.z); pf[3] = (short)f2bs(pa0.w);
    pf[4] = (short)f2bs(pa1.x); pf[5] = (short)f2bs(pa1.y);
    pf[6] = (short)f2bs(pa1.z); pf[7] = (short)f2bs(pa1.w);
    v8s vb = *(const v8s*)(vbase + ny * 32 + q * 8);
    oacc = __builtin_amdgcn_mfma_f32_16x16x32_bf16(pf, vb, oacc, 0, 0, 0);
  }

#pragma unroll
  for (int r = 0; r < 4; ++r) {
    float s = ssum[r];
    s += __shfl_xor(s, 1); s += __shfl_xor(s, 2);
    s += __shfl_xor(s, 4); s += __shfl_xor(s, 8);
    ssum[r] = s;
  }
  unsigned short* abase = (b < 6) ? (dq + ART1_US + (size_t)b * 131072)
                                  : (wsart + (size_t)(b - 6) * 131072);
#pragma unroll
  for (int r = 0; r < 4; ++r) {
    int m = m0 + q * 4 + r;
    int c = h * 16 + (m >> 6);
    int pp = (m & 63) * 16 + il;
    abase[pp * 128 + c] = f2bs(oacc[r] / ssum[r]);
  }
}

// ---------------------------------------------------------------------------
// attn_out GEMM: out[b][384+co][pos'] = art[b][pos'][128ci] * watt^T + bias.
__global__ __launch_bounds__(64) void attn_out_mfma(
    const unsigned short* __restrict__ dq, const unsigned short* __restrict__ wsart,
    const unsigned short* __restrict__ wattb, const float* __restrict__ ba,
    float* __restrict__ out) {
  int lane = threadIdx.x; int il = lane & 15, q = lane >> 4;
  int m0 = blockIdx.x * 64, co0 = blockIdx.y * 64;
  int b = m0 >> 10, pp0 = m0 & 1023;
  const unsigned short* ab = ((b < 6) ? (dq + ART1_US + (size_t)b * 131072)
                                      : (wsart + (size_t)(b - 6) * 131072))
                             + (pp0 + il) * 128 + q * 8;
  const unsigned short* bb = wattb + (co0 + il) * 128 + q * 8;
  v4f acc[4][4];
#pragma unroll
  for (int mt = 0; mt < 4; ++mt)
#pragma unroll
    for (int nt = 0; nt < 4; ++nt) acc[mt][nt] = (v4f){0.f, 0.f, 0.f, 0.f};
  for (int kc = 0; kc < 4; ++kc) {
    v8s af[4], bf[4];
#pragma unroll
    for (int mt = 0; mt < 4; ++mt) af[mt] = *(const v8s*)(ab + mt * 2048 + kc * 32);
#pragma unroll
    for (int nt = 0; nt < 4; ++nt) bf[nt] = *(const v8s*)(bb + nt * 2048 + kc * 32);
#pragma unroll
    for (int mt = 0; mt < 4; ++mt)
#pragma unroll
      for (int nt = 0; nt < 4; ++nt)
        acc[mt][nt] = __builtin_amdgcn_mfma_f32_16x16x32_bf16(
            af[mt], bf[nt], acc[mt][nt], 0, 0, 0);
  }
#pragma unroll
  for (int nt = 0; nt < 4; ++nt) {
    int co = co0 + nt * 16 + il;
    float bias = ba[co];
#pragma unroll
    for (int mt = 0; mt < 4; ++mt) {
      v4f a = acc[mt][nt];
      float4 v; v.x = a[0] + bias; v.y = a[1] + bias;
      v.z = a[2] + bias; v.w = a[3] + bias;
      *(float4*)(out + ((size_t)(b * 512 + 384 + co)) * 1024 + pp0 + mt * 16 + q * 4) = v;
    }
  }
}

// ---------------------------------------------------------------------------
// conv3x3 via MFMA, all 9 taps in one wave; direct bias+store (no atomics).
__global__ __launch_bounds__(64) void conv_mfma(
    const unsigned short* __restrict__ xt, const unsigned short* __restrict__ wbf,
    const float* __restrict__ bo, float* __restrict__ out) {
  int lane = threadIdx.x; int il = lane & 15, q = lane >> 4;
  int pt = blockIdx.x, ct = blockIdx.y, b = blockIdx.z;
  int pos0 = pt * 64, co0 = ct * 64;
  int row0 = pos0 >> 5;
  v4f acc[4][4];
#pragma unroll
  for (int mt = 0; mt < 4; ++mt)
#pragma unroll
    for (int nt = 0; nt < 4; ++nt) acc[mt][nt] = (v4f){0.f, 0.f, 0.f, 0.f};
  const v8s z8 = {0, 0, 0, 0, 0, 0, 0, 0};
  const unsigned short* bb = wbf + ((size_t)(co0 + il)) * 256 + q * 8;

  for (int ky = 0; ky < 3; ++ky) {
    const unsigned short* abase[4];
    bool rok[4];
#pragma unroll
    for (int mt = 0; mt < 4; ++mt) {
      int rowp = row0 + (mt >> 1) + ky - 1;
      rok[mt] = ((unsigned)rowp) < 32u;
      int colb = (mt & 1) * 16 + il - 1;
      long off = ((long)(b * 1024) + (long)rowp * 32 + colb) * 256 + q * 8;
      abase[mt] = xt + off;
    }
#pragma unroll
    for (int kx = 0; kx < 3; ++kx) {
      const unsigned short* bt = bb + (size_t)(ky * 3 + kx) * 98304;
      for (int kc = 0; kc < 8; ++kc) {
        v8s bf[4];
#pragma unroll
        for (int nt = 0; nt < 4; ++nt)
          bf[nt] = *(const v8s*)(bt + nt * 4096 + kc * 32);
        v8s af[4];
#pragma unroll
        for (int mt = 0; mt < 4; ++mt) {
          bool ok = rok[mt];
          if (kx == 0) ok = ok && !((il == 0) && ((mt & 1) == 0));
          if (kx == 2) ok = ok && !((il == 15) && ((mt & 1) == 1));
          const v8s* p = (const v8s*)(abase[mt] + kx * 256 + kc * 32);
          p = ok ? p : (const v8s*)xt;
          v8s a = *p;
          af[mt] = ok ? a : z8;
        }
#pragma unroll
        for (int mt = 0; mt < 4; ++mt)
#pragma unroll
          for (int nt = 0; nt < 4; ++nt)
            acc[mt][nt] = __builtin_amdgcn_mfma_f32_16x16x32_bf16(
                af[mt], bf[nt], acc[mt][nt], 0, 0, 0);
      }
    }
  }
#pragma unroll
  for (int nt = 0; nt < 4; ++nt) {
    int co = co0 + nt * 16 + il;
    float bias = bo[co];
#pragma unroll
    for (int mt = 0; mt < 4; ++mt) {
      v4f a = acc[mt][nt];
      float4 v; v.x = a[0] + bias; v.y = a[1] + bias;
      v.z = a[2] + bias; v.w = a[3] + bias;
      *(float4*)(out + ((size_t)(b * 512 + co)) * 1024 + pos0 + mt * 16 + q * 4) = v;
    }
  }
}

// ---------------------------------------------------------------------------
extern "C" void kernel_launch(void* const* d_in, const int* in_sizes, int n_in,
                              void* d_out, int out_size, void* d_ws, size_t ws_size,
                              hipStream_t stream) {
  const float* x      = (const float*)d_in[0];
  const float* b_out  = (const float*)d_in[2];
  const float* b_kqv  = (const float*)d_in[4];
  const float* b_attn = (const float*)d_in[6];
  const float* krw    = (const float*)d_in[7];
  const float* krh    = (const float*)d_in[8];
  unsigned short* ws = (unsigned short*)d_ws;
  float* out = (float*)d_out;
  unsigned short* dq = (unsigned short*)d_out;

  prep_kernel<<<3912, 256, 0, stream>>>(
      (const float*)d_in[1], (const float*)d_in[3], (const float*)d_in[5],
      krw, krh, ws);
  xt_kernel<<<dim3(16, 4, 8), 256, 0, stream>>>(x, ws + XT_US);
  kqv_mfma<<<dim3(128, 6), 64, 0, stream>>>(
      ws + XT_US, ws + WKQVB_US, b_kqv, dq);
  attn_mfma<<<dim3(16, 64), 256, 0, stream>>>(
      dq, ws + KRWB_US, ws + KRHB_US, ws + ART2_US);
  attn_out_mfma<<<dim3(128, 2), 64, 0, stream>>>(
      dq, ws + ART2_US, ws + WATTB_US, b_attn, out);
  conv_mfma<<<dim3(16, 6, 8), 64, 0, stream>>>(
      ws + XT_US, ws + WBF_US, b_out, out);
}

// Round 7
// 209.446 us; speedup vs baseline: 8.8636x; 1.0392x over previous
//
#include <hip/hip_runtime.h>
#include <hip/hip_bf16.h>

// ---------------------------------------------------------------------------
// SelfAttention2d, fully-MFMA pipeline. Inputs fp32, output fp32.
// MFMA 16x16x32 bf16 layouts (verified rounds 5/6):
//   A[m=lane&15][k=(lane>>4)*8+j], B[col=lane&15][k=(lane>>4)*8+j],
//   C[row=(lane>>4)*4+reg][col=lane&15]
// Softmax in exp2 domain: q pre-scaled by 0.25*log2(e); fixed shift folded
// into the PH table.
//
// x is stored ZERO-PADDED + transposed: xtp[b][row 0..33][col 0..33][ci] bf16,
// interior pixel (y,x) at (y+1,x+1). Conv A-frag addresses become fully
// regular (no edge masks -> loads cluster/pipeline).
//
// ws (ushort units, total 7,262,208 B <= proven-safe 8,192,000):
//   WBF 0            w_out bf16 [t9][co384][ci256]
//   WKQVB 884736     w_kqv bf16 [co384][ci256]
//   WATTB 983040     w_attn bf16 [co128][ci128]
//   KRWB 999424      krw bf16 [64][16] (row63=0)   KRHB 1000448 same
//   XTP 1001472      x bf16 padded [b][34][34][256]  (2,367,488 us)
//   ART2 3368960     art slots b=6,7 (262144 us)
// d_out (8388608 us): KS 0 / QS 1048576 / VTS 2097152 (dead after attn);
//   ART1 7340032 = b7 ch0..383 region, slots b=0..5.
// Order: prep -> zero_xtp -> xt -> kqv -> attn -> attn_out -> conv
// ---------------------------------------------------------------------------

typedef short v8s __attribute__((ext_vector_type(8)));
typedef float v4f __attribute__((ext_vector_type(4)));

#define WBF_US   0u
#define WKQVB_US 884736u
#define WATTB_US 983040u
#define KRWB_US  999424u
#define KRHB_US  1000448u
#define XTP_US   1001472u
#define ART2_US  3368960u

#define KS_US    0u
#define QS_US    1048576u
#define VTS_US   2097152u
#define ART1_US  7340032u

#define QSCALE 0.360673760f   // 0.25 * log2(e)
#define SHIFT2 17.3123405f    // 12 * log2(e)

__device__ __forceinline__ unsigned short f2bs(float f) {
  __hip_bfloat16 h = __float2bfloat16(f);
  return *reinterpret_cast<unsigned short*>(&h);
}

// ---------------------------------------------------------------------------
__global__ __launch_bounds__(256) void prep_kernel(
    const float* __restrict__ w_out, const float* __restrict__ w_kqv,
    const float* __restrict__ w_attn, const float* __restrict__ krw,
    const float* __restrict__ krh, unsigned short* __restrict__ ws) {
  int i = blockIdx.x * 256 + threadIdx.x;
  if (i < 884736) {              // wbf[(t*384+co)*256+ci] = w_out[co][ci][t]
    int ci = i & 255, r = i >> 8;
    int co = r % 384, t = r / 384;
    ws[WBF_US + i] = f2bs(w_out[(size_t)co * 2304 + ci * 9 + t]);
  } else if (i < 983040) {       // direct cast [co][ci]
    int j = i - 884736;
    ws[WKQVB_US + j] = f2bs(w_kqv[j]);
  } else if (i < 999424) {       // direct cast [co][ci]
    int j = i - 983040;
    ws[WATTB_US + j] = f2bs(w_attn[j]);
  } else if (i < 1000448) {      // krw bf16 [64][16], row 63 zero
    int j = i - 999424; int c = j >> 4, d = j & 15;
    ws[KRWB_US + j] = (c < 63) ? f2bs(krw[c * 16 + d]) : (unsigned short)0;
  } else if (i < 1001472) {
    int j = i - 1000448; int c = j >> 4, d = j & 15;
    ws[KRHB_US + j] = (c < 63) ? f2bs(krh[c * 16 + d]) : (unsigned short)0;
  }
}

// ---------------------------------------------------------------------------
// zero the whole padded x buffer (ws is re-poisoned before every launch).
__global__ __launch_bounds__(256) void zero_xtp_kernel(unsigned short* __restrict__ xtp) {
  int i = blockIdx.x * 256 + threadIdx.x;   // 295,936 uint4 = 2,367,488 us
  uint4 z = {0u, 0u, 0u, 0u};
  ((uint4*)xtp)[i] = z;
}

// ---------------------------------------------------------------------------
// xT: [b][ci][pos] fp32 -> padded [b][y+1][x+1][ci] bf16 via LDS 64x64 tile.
__global__ __launch_bounds__(256) void xt_kernel(
    const float* __restrict__ x, unsigned short* __restrict__ xtp) {
  __shared__ float t[64][65];
  int tid = threadIdx.x; int pl = tid & 63, cg = tid >> 6;
  int pos0 = blockIdx.x * 64, ci0 = blockIdx.y * 64, b = blockIdx.z;
  const float* xb = x + ((size_t)(b * 256 + ci0)) * 1024 + pos0;
#pragma unroll
  for (int i = 0; i < 16; ++i) {
    int ci_l = cg * 16 + i;
    t[ci_l][pl] = xb[(size_t)ci_l * 1024 + pl];
  }
  __syncthreads();
#pragma unroll
  for (int i = 0; i < 16; ++i) {
    int pos_l = cg * 16 + i;
    int pos = pos0 + pos_l;
    int y = pos >> 5, xx = pos & 31;
    xtp[(((size_t)(b * 34) + y + 1) * 34 + xx + 1) * 256 + ci0 + pl] =
        f2bs(t[pl][pos_l]);
  }
}

// ---------------------------------------------------------------------------
// kqv GEMM: [8192 pos][384 co] = x[pos][256] * wkqv^T. 64x64 tile per wave.
// A-frags from padded xtp at (+1,+1). Scatters bf16 into KS/QS/VTS.
__global__ __launch_bounds__(64) void kqv_mfma(
    const unsigned short* __restrict__ xtp,
    const unsigned short* __restrict__ wkqvb,
    const float* __restrict__ bkqv, unsigned short* __restrict__ dq) {
  int lane = threadIdx.x; int il = lane & 15, q = lane >> 4;
  int m0 = blockIdx.x * 64, co0 = blockIdx.y * 64;
  int b = m0 >> 10, pos0 = m0 & 1023;
  int row0 = pos0 >> 5;
  v4f acc[4][4];
#pragma unroll
  for (int mt = 0; mt < 4; ++mt)
#pragma unroll
    for (int nt = 0; nt < 4; ++nt) acc[mt][nt] = (v4f){0.f, 0.f, 0.f, 0.f};

  const unsigned short* ab[4];
#pragma unroll
  for (int mt = 0; mt < 4; ++mt) {
    int y = row0 + (mt >> 1) + 1;
    int xx = (mt & 1) * 16 + il + 1;
    ab[mt] = xtp + (((size_t)(b * 34) + y) * 34 + xx) * 256 + q * 8;
  }
  const unsigned short* bb = wkqvb + (size_t)(co0 + il) * 256 + q * 8;
  for (int kc = 0; kc < 8; ++kc) {
    v8s af[4], bf[4];
#pragma unroll
    for (int mt = 0; mt < 4; ++mt) af[mt] = *(const v8s*)(ab[mt] + kc * 32);
#pragma unroll
    for (int nt = 0; nt < 4; ++nt) bf[nt] = *(const v8s*)(bb + nt * 4096 + kc * 32);
#pragma unroll
    for (int mt = 0; mt < 4; ++mt)
#pragma unroll
      for (int nt = 0; nt < 4; ++nt)
        acc[mt][nt] = __builtin_amdgcn_mfma_f32_16x16x32_bf16(
            af[mt], bf[nt], acc[mt][nt], 0, 0, 0);
  }
#pragma unroll
  for (int nt = 0; nt < 4; ++nt) {
    int cob = co0 + nt * 16;
    int co = cob + il;
    float bias = bkqv[co];
    int cls = cob >> 7;                  // 0:k 1:q 2:v (uniform per nt)
    int h = (cob >> 4) & 7;
    size_t bh = (size_t)(b * 8 + h);
#pragma unroll
    for (int mt = 0; mt < 4; ++mt) {
      int pos = pos0 + mt * 16 + q * 4;
      v4f a = acc[mt][nt];
#pragma unroll
      for (int r = 0; r < 4; ++r) {
        float v = a[r] + bias;
        int p = pos + r;
        if (cls == 0)      dq[KS_US + bh * 16384 + p * 16 + il] = f2bs(v);
        else if (cls == 1) dq[QS_US + bh * 16384 + p * 16 + il] = f2bs(v * QSCALE);
        else               dq[VTS_US + bh * 16384 + il * 1024 + p] = f2bs(v);
      }
    }
  }
}

// ---------------------------------------------------------------------------
// MFMA attention. Block 256 = 4 waves; wave owns 16-row m-tile.
__global__ __launch_bounds__(256) void attn_mfma(
    unsigned short* __restrict__ dq, const unsigned short* __restrict__ krwb,
    const unsigned short* __restrict__ krhb, unsigned short* __restrict__ wsart) {
  __shared__ float lds[4][2688];
  int tid = threadIdx.x; int w = tid >> 6, lane = tid & 63;
  int il = lane & 15, q = lane >> 4;
  int bh = blockIdx.y; int b = bh >> 3, h = bh & 7;
  int m0 = blockIdx.x * 64 + w * 16;
  int my = m0 >> 5, mxb = m0 & 31;
  float* pw = lds[w];
  float* ph = pw + 1024;
  float* pl = ph + 1088;

  const v8s z8 = {0, 0, 0, 0, 0, 0, 0, 0};
  const v4f z4 = {0.f, 0.f, 0.f, 0.f};

  // Q A-frag (K=16, quads 2,3 zero)
  const unsigned short* qrow = dq + QS_US + (size_t)bh * 16384 + (m0 + il) * 16;
  v8s qa = *(const v8s*)(qrow + (q & 1) * 8);
  qa = (q < 2) ? qa : z8;

  // PW / PH tables via MFMA
#pragma unroll
  for (int nt = 0; nt < 4; ++nt) {
    int c = nt * 16 + il;
    v8s bw = *(const v8s*)(krwb + c * 16 + (q & 1) * 8);
    v8s bhh = *(const v8s*)(krhb + c * 16 + (q & 1) * 8);
    bw = (q < 2) ? bw : z8;
    bhh = (q < 2) ? bhh : z8;
    v4f pwc = __builtin_amdgcn_mfma_f32_16x16x32_bf16(qa, bw, z4, 0, 0, 0);
    v4f phc = __builtin_amdgcn_mfma_f32_16x16x32_bf16(qa, bhh, z4, 0, 0, 0);
#pragma unroll
    for (int r = 0; r < 4; ++r) {
      pw[(q * 4 + r) * 63 + c] = pwc[r];
      ph[(q * 4 + r) * 68 + c] = phc[r] - SHIFT2;
    }
  }

  v4f oacc = z4;
  float ssum[4] = {0.f, 0.f, 0.f, 0.f};
  const unsigned short* kbase = dq + KS_US + (size_t)bh * 16384;
  const unsigned short* vbase = dq + VTS_US + (size_t)bh * 16384 + il * 1024;
  int ibase = il + 31 - mxb - q * 4;

  for (int ny = 0; ny < 32; ++ny) {
    int idxh = ny - my + 31;
    float phr[4];
#pragma unroll
    for (int r = 0; r < 4; ++r) phr[r] = ph[(q * 4 + r) * 68 + idxh];
#pragma unroll
    for (int nt2 = 0; nt2 < 2; ++nt2) {
      int nb = ny * 32 + nt2 * 16;
      v8s kb = *(const v8s*)(kbase + (nb + il) * 16 + (q & 1) * 8);
      kb = (q < 2) ? kb : z8;
      v4f s = __builtin_amdgcn_mfma_f32_16x16x32_bf16(qa, kb, z4, 0, 0, 0);
#pragma unroll
      for (int r = 0; r < 4; ++r) {
        float pwv = pw[(q * 4 + r) * 63 + (ibase + nt2 * 16 - r)];
        float t = s[r] + pwv + phr[r];
        float p = exp2f(t);
        ssum[r] += p;
        pl[(q * 4 + r) * 36 + nt2 * 16 + il] = p;
      }
    }
    float4 pa0 = *(const float4*)(pl + il * 36 + q * 8);
    float4 pa1 = *(const float4*)(pl + il * 36 + q * 8 + 4);
    v8s pf;
    pf[0] = (short)f2bs(pa0.x); pf[1] = (short)f2bs(pa0.y);
    pf[2] = (short)f2bs(pa0.z); pf[3] = (short)f2bs(pa0.w);
    pf[4] = (short)f2bs(pa1.x); pf[5] = (short)f2bs(pa1.y);
    pf[6] = (short)f2bs(pa1.z); pf[7] = (short)f2bs(pa1.w);
    v8s vb = *(const v8s*)(vbase + ny * 32 + q * 8);
    oacc = __builtin_amdgcn_mfma_f32_16x16x32_bf16(pf, vb, oacc, 0, 0, 0);
  }

#pragma unroll
  for (int r = 0; r < 4; ++r) {
    float s = ssum[r];
    s += __shfl_xor(s, 1); s += __shfl_xor(s, 2);
    s += __shfl_xor(s, 4); s += __shfl_xor(s, 8);
    ssum[r] = s;
  }
  unsigned short* abase = (b < 6) ? (dq + ART1_US + (size_t)b * 131072)
                                  : (wsart + (size_t)(b - 6) * 131072);
#pragma unroll
  for (int r = 0; r < 4; ++r) {
    int m = m0 + q * 4 + r;
    int c = h * 16 + (m >> 6);
    int pp = (m & 63) * 16 + il;
    abase[pp * 128 + c] = f2bs(oacc[r] / ssum[r]);
  }
}

// ---------------------------------------------------------------------------
// attn_out GEMM: out[b][384+co][pos'] = art[b][pos'][128ci] * watt^T + bias.
__global__ __launch_bounds__(64) void attn_out_mfma(
    const unsigned short* __restrict__ dq, const unsigned short* __restrict__ wsart,
    const unsigned short* __restrict__ wattb, const float* __restrict__ ba,
    float* __restrict__ out) {
  int lane = threadIdx.x; int il = lane & 15, q = lane >> 4;
  int m0 = blockIdx.x * 64, co0 = blockIdx.y * 64;
  int b = m0 >> 10, pp0 = m0 & 1023;
  const unsigned short* ab = ((b < 6) ? (dq + ART1_US + (size_t)b * 131072)
                                      : (wsart + (size_t)(b - 6) * 131072))
                             + (pp0 + il) * 128 + q * 8;
  const unsigned short* bb = wattb + (co0 + il) * 128 + q * 8;
  v4f acc[4][4];
#pragma unroll
  for (int mt = 0; mt < 4; ++mt)
#pragma unroll
    for (int nt = 0; nt < 4; ++nt) acc[mt][nt] = (v4f){0.f, 0.f, 0.f, 0.f};
  for (int kc = 0; kc < 4; ++kc) {
    v8s af[4], bf[4];
#pragma unroll
    for (int mt = 0; mt < 4; ++mt) af[mt] = *(const v8s*)(ab + mt * 2048 + kc * 32);
#pragma unroll
    for (int nt = 0; nt < 4; ++nt) bf[nt] = *(const v8s*)(bb + nt * 2048 + kc * 32);
#pragma unroll
    for (int mt = 0; mt < 4; ++mt)
#pragma unroll
      for (int nt = 0; nt < 4; ++nt)
        acc[mt][nt] = __builtin_amdgcn_mfma_f32_16x16x32_bf16(
            af[mt], bf[nt], acc[mt][nt], 0, 0, 0);
  }
#pragma unroll
  for (int nt = 0; nt < 4; ++nt) {
    int co = co0 + nt * 16 + il;
    float bias = ba[co];
#pragma unroll
    for (int mt = 0; mt < 4; ++mt) {
      v4f a = acc[mt][nt];
      float4 v; v.x = a[0] + bias; v.y = a[1] + bias;
      v.z = a[2] + bias; v.w = a[3] + bias;
      *(float4*)(out + ((size_t)(b * 512 + 384 + co)) * 1024 + pp0 + mt * 16 + q * 4) = v;
    }
  }
}

// ---------------------------------------------------------------------------
// conv3x3 via MFMA on padded xtp: all loads unconditional & regular.
__global__ __launch_bounds__(64) void conv_mfma(
    const unsigned short* __restrict__ xtp, const unsigned short* __restrict__ wbf,
    const float* __restrict__ bo, float* __restrict__ out) {
  int lane = threadIdx.x; int il = lane & 15, q = lane >> 4;
  int pt = blockIdx.x, ct = blockIdx.y, b = blockIdx.z;
  int pos0 = pt * 64, co0 = ct * 64;
  int row0 = pos0 >> 5;
  v4f acc[4][4];
#pragma unroll
  for (int mt = 0; mt < 4; ++mt)
#pragma unroll
    for (int nt = 0; nt < 4; ++nt) acc[mt][nt] = (v4f){0.f, 0.f, 0.f, 0.f};
  const unsigned short* bb = wbf + ((size_t)(co0 + il)) * 256 + q * 8;

#pragma unroll
  for (int ky = 0; ky < 3; ++ky) {
#pragma unroll
    for (int kx = 0; kx < 3; ++kx) {
      const unsigned short* bt = bb + (size_t)(ky * 3 + kx) * 98304;
      const unsigned short* at[4];
#pragma unroll
      for (int mt = 0; mt < 4; ++mt) {
        int y = row0 + (mt >> 1) + ky;        // padded row
        int xx = (mt & 1) * 16 + il + kx;     // padded col
        at[mt] = xtp + (((size_t)(b * 34) + y) * 34 + xx) * 256 + q * 8;
      }
#pragma unroll 2
      for (int kc = 0; kc < 8; ++kc) {
        v8s bf[4], af[4];
#pragma unroll
        for (int nt = 0; nt < 4; ++nt)
          bf[nt] = *(const v8s*)(bt + nt * 4096 + kc * 32);
#pragma unroll
        for (int mt = 0; mt < 4; ++mt)
          af[mt] = *(const v8s*)(at[mt] + kc * 32);
#pragma unroll
        for (int mt = 0; mt < 4; ++mt)
#pragma unroll
          for (int nt = 0; nt < 4; ++nt)
            acc[mt][nt] = __builtin_amdgcn_mfma_f32_16x16x32_bf16(
                af[mt], bf[nt], acc[mt][nt], 0, 0, 0);
      }
    }
  }
#pragma unroll
  for (int nt = 0; nt < 4; ++nt) {
    int co = co0 + nt * 16 + il;
    float bias = bo[co];
#pragma unroll
    for (int mt = 0; mt < 4; ++mt) {
      v4f a = acc[mt][nt];
      float4 v; v.x = a[0] + bias; v.y = a[1] + bias;
      v.z = a[2] + bias; v.w = a[3] + bias;
      *(float4*)(out + ((size_t)(b * 512 + co)) * 1024 + pos0 + mt * 16 + q * 4) = v;
    }
  }
}

// ---------------------------------------------------------------------------
extern "C" void kernel_launch(void* const* d_in, const int* in_sizes, int n_in,
                              void* d_out, int out_size, void* d_ws, size_t ws_size,
                              hipStream_t stream) {
  const float* x      = (const float*)d_in[0];
  const float* b_out  = (const float*)d_in[2];
  const float* b_kqv  = (const float*)d_in[4];
  const float* b_attn = (const float*)d_in[6];
  const float* krw    = (const float*)d_in[7];
  const float* krh    = (const float*)d_in[8];
  unsigned short* ws = (unsigned short*)d_ws;
  float* out = (float*)d_out;
  unsigned short* dq = (unsigned short*)d_out;

  prep_kernel<<<3912, 256, 0, stream>>>(
      (const float*)d_in[1], (const float*)d_in[3], (const float*)d_in[5],
      krw, krh, ws);
  zero_xtp_kernel<<<1156, 256, 0, stream>>>(ws + XTP_US);
  xt_kernel<<<dim3(16, 4, 8), 256, 0, stream>>>(x, ws + XTP_US);
  kqv_mfma<<<dim3(128, 6), 64, 0, stream>>>(
      ws + XTP_US, ws + WKQVB_US, b_kqv, dq);
  attn_mfma<<<dim3(16, 64), 256, 0, stream>>>(
      dq, ws + KRWB_US, ws + KRHB_US, ws + ART2_US);
  attn_out_mfma<<<dim3(128, 2), 64, 0, stream>>>(
      dq, ws + ART2_US, ws + WATTB_US, b_attn, out);
  conv_mfma<<<dim3(16, 6, 8), 64, 0, stream>>>(
      ws + XTP_US, ws + WBF_US, b_out, out);
}

// Round 8
// 189.267 us; speedup vs baseline: 9.8086x; 1.1066x over previous
//
#include <hip/hip_runtime.h>
#include <hip/hip_bf16.h>

// ---------------------------------------------------------------------------
// SelfAttention2d, fully-MFMA pipeline, fragment-major memory layouts.
// MFMA 16x16x32 bf16: A[m=il][k=q*8+j], B[col=il][k=q*8+j], C[row=q*4+r][col=il]
//
// Key layouts (all chosen so a wave's frag load is one contiguous 1KB):
//   XC   [b][kc 0..7][y 0..33][x 0..33][ci 32]  zero-padded image, bf16
//   WB2  [t9][coG6][nt4][kc8][lane64][8]        w_out frag-major
//   WK2  [coG6][nt4][kc8][lane64][8]            w_kqv frag-major
//   WA2  [coG2][nt4][kc4][lane64][8]            w_attn frag-major
//   VT   [bh][ny32][d16][ci 32]                 V^T frag-major
//   artX [b][kc4][pp1024][ci32]                 attn out, frag-major for reuse
//
// ws (ushort units, 7,262,208 B <= proven-safe 8,192,000):
//   WB2 0 / WK2 884736 / WA2 983040 / KRWB 999424 / KRHB 1000448 /
//   XC 1001472 (2,367,488) / ART2 3368960 (b=6,7 slots)
// d_out scratch (ushort): KS 0 / QS 1048576 / VT 2097152 / ART1 7340032 (b0..5)
// Order: prep -> zero_xc -> xt -> kqv -> attn -> attn_out -> conv
// ---------------------------------------------------------------------------

typedef short v8s __attribute__((ext_vector_type(8)));
typedef float v4f __attribute__((ext_vector_type(4)));

#define WB2_US   0u
#define WK2_US   884736u
#define WA2_US   983040u
#define KRWB_US  999424u
#define KRHB_US  1000448u
#define XC_US    1001472u
#define ART2_US  3368960u

#define KS_US    0u
#define QS_US    1048576u
#define VTS_US   2097152u
#define ART1_US  7340032u

#define QSCALE 0.360673760f   // 0.25 * log2(e)
#define SHIFT2 17.3123405f    // 12 * log2(e)

__device__ __forceinline__ unsigned short f2bs(float f) {
  __hip_bfloat16 h = __float2bfloat16(f);
  return *reinterpret_cast<unsigned short*>(&h);
}

// ---------------------------------------------------------------------------
__global__ __launch_bounds__(256) void prep_kernel(
    const float* __restrict__ w_out, const float* __restrict__ w_kqv,
    const float* __restrict__ w_attn, const float* __restrict__ krw,
    const float* __restrict__ krh, unsigned short* __restrict__ ws) {
  int i = blockIdx.x * 256 + threadIdx.x;
  if (i < 884736) {              // WB2[t][coG][nt][kc][lane][8]
    int j = i & 7, l = (i >> 3) & 63, kc = (i >> 9) & 7, nt = (i >> 12) & 3;
    int r = i >> 14; int coG = r % 6, t = r / 6;
    int co = coG * 64 + nt * 16 + (l & 15);
    int ci = kc * 32 + (l >> 4) * 8 + j;
    ws[WB2_US + i] = f2bs(w_out[(size_t)co * 2304 + ci * 9 + t]);
  } else if (i < 983040) {       // WK2[coG][nt][kc][lane][8]
    int o = i - 884736;
    int j = o & 7, l = (o >> 3) & 63, kc = (o >> 9) & 7, nt = (o >> 12) & 3;
    int coG = o >> 14;
    int co = coG * 64 + nt * 16 + (l & 15);
    int ci = kc * 32 + (l >> 4) * 8 + j;
    ws[WK2_US + o] = f2bs(w_kqv[co * 256 + ci]);
  } else if (i < 999424) {       // WA2[coG][nt][kc][lane][8]
    int o = i - 983040;
    int j = o & 7, l = (o >> 3) & 63, kc = (o >> 9) & 3, nt = (o >> 11) & 3;
    int coG = o >> 13;
    int co = coG * 64 + nt * 16 + (l & 15);
    int ci = kc * 32 + (l >> 4) * 8 + j;
    ws[WA2_US + o] = f2bs(w_attn[co * 128 + ci]);
  } else if (i < 1000448) {      // krw bf16 [64][16], row 63 zero
    int j = i - 999424; int c = j >> 4, d = j & 15;
    ws[KRWB_US + j] = (c < 63) ? f2bs(krw[c * 16 + d]) : (unsigned short)0;
  } else if (i < 1001472) {
    int j = i - 1000448; int c = j >> 4, d = j & 15;
    ws[KRHB_US + j] = (c < 63) ? f2bs(krh[c * 16 + d]) : (unsigned short)0;
  }
}

// ---------------------------------------------------------------------------
__global__ __launch_bounds__(256) void zero_xc_kernel(unsigned short* __restrict__ xc) {
  int i = blockIdx.x * 256 + threadIdx.x;   // 295,936 uint4 = 2,367,488 us
  uint4 z = {0u, 0u, 0u, 0u};
  ((uint4*)xc)[i] = z;
}

// ---------------------------------------------------------------------------
// x [b][ci][pos] fp32 -> XC[b][ci>>5][y+1][x+1][ci&31] bf16 via LDS tile.
__global__ __launch_bounds__(256) void xt_kernel(
    const float* __restrict__ x, unsigned short* __restrict__ xc) {
  __shared__ float t[64][65];
  int tid = threadIdx.x; int pl = tid & 63, cg = tid >> 6;
  int pos0 = blockIdx.x * 64, ci0 = blockIdx.y * 64, b = blockIdx.z;
  const float* xb = x + ((size_t)(b * 256 + ci0)) * 1024 + pos0;
#pragma unroll
  for (int i = 0; i < 16; ++i) {
    int ci_l = cg * 16 + i;
    t[ci_l][pl] = xb[(size_t)ci_l * 1024 + pl];
  }
  __syncthreads();
#pragma unroll
  for (int i = 0; i < 16; ++i) {
    int pos_l = cg * 16 + i;
    int pos = pos0 + pos_l;
    int y = (pos >> 5) + 1, xx = (pos & 31) + 1;
    int ci = ci0 + pl;
    xc[((size_t)((b * 8 + (ci >> 5)) * 34 + y) * 34 + xx) * 32 + (ci & 31)] =
        f2bs(t[pl][pos_l]);
  }
}

// ---------------------------------------------------------------------------
// kqv GEMM: A-frags from XC (tap 1,1; contiguous 1KB loads), B from WK2.
__global__ __launch_bounds__(64) void kqv_mfma(
    const unsigned short* __restrict__ xc, const unsigned short* __restrict__ wk2,
    const float* __restrict__ bkqv, unsigned short* __restrict__ dq) {
  int lane = threadIdx.x; int il = lane & 15, q = lane >> 4;
  int m0 = blockIdx.x * 64, coG = blockIdx.y;
  int b = m0 >> 10, pos0 = m0 & 1023;
  int row0 = pos0 >> 5;
  v4f acc[4][4];
#pragma unroll
  for (int mt = 0; mt < 4; ++mt)
#pragma unroll
    for (int nt = 0; nt < 4; ++nt) acc[mt][nt] = (v4f){0.f, 0.f, 0.f, 0.f};

  int pix[4];
#pragma unroll
  for (int mt = 0; mt < 4; ++mt)
    pix[mt] = (row0 + (mt >> 1) + 1) * 34 + ((mt & 1) * 16 + il + 1);
  const unsigned short* bt = wk2 + (size_t)coG * 16384 + lane * 8;

#pragma unroll 2
  for (int kc = 0; kc < 8; ++kc) {
    v8s af[4], bf[4];
#pragma unroll
    for (int nt = 0; nt < 4; ++nt)
      bf[nt] = *(const v8s*)(bt + (nt * 8 + kc) * 512);
#pragma unroll
    for (int mt = 0; mt < 4; ++mt)
      af[mt] = *(const v8s*)(xc + ((size_t)(b * 8 + kc) * 1156 + pix[mt]) * 32 + q * 8);
#pragma unroll
    for (int mt = 0; mt < 4; ++mt)
#pragma unroll
      for (int nt = 0; nt < 4; ++nt)
        acc[mt][nt] = __builtin_amdgcn_mfma_f32_16x16x32_bf16(
            af[mt], bf[nt], acc[mt][nt], 0, 0, 0);
  }
  int co0 = coG * 64;
#pragma unroll
  for (int nt = 0; nt < 4; ++nt) {
    int cob = co0 + nt * 16;
    int co = cob + il;
    float bias = bkqv[co];
    int cls = cob >> 7;                  // 0:k 1:q 2:v (uniform per nt)
    int h = (cob >> 4) & 7;
    size_t bh = (size_t)(b * 8 + h);
#pragma unroll
    for (int mt = 0; mt < 4; ++mt) {
      int pos = pos0 + mt * 16 + q * 4;
      v4f a = acc[mt][nt];
#pragma unroll
      for (int r = 0; r < 4; ++r) {
        float v = a[r] + bias;
        int p = pos + r;
        if (cls == 0)      dq[KS_US + bh * 16384 + p * 16 + il] = f2bs(v);
        else if (cls == 1) dq[QS_US + bh * 16384 + p * 16 + il] = f2bs(v * QSCALE);
        else               dq[VTS_US + bh * 16384 + ((p >> 5) * 16 + il) * 32 + (p & 31)] = f2bs(v);
      }
    }
  }
}

// ---------------------------------------------------------------------------
// MFMA attention. Block 256 = 4 waves; wave owns 16-row m-tile.
__global__ __launch_bounds__(256) void attn_mfma(
    unsigned short* __restrict__ dq, const unsigned short* __restrict__ krwb,
    const unsigned short* __restrict__ krhb, unsigned short* __restrict__ wsart) {
  __shared__ float lds[4][2688];
  int tid = threadIdx.x; int w = tid >> 6, lane = tid & 63;
  int il = lane & 15, q = lane >> 4;
  int bh = blockIdx.y; int b = bh >> 3, h = bh & 7;
  int m0 = blockIdx.x * 64 + w * 16;
  int my = m0 >> 5, mxb = m0 & 31;
  float* pw = lds[w];
  float* ph = pw + 1024;
  float* pl = ph + 1088;

  const v8s z8 = {0, 0, 0, 0, 0, 0, 0, 0};
  const v4f z4 = {0.f, 0.f, 0.f, 0.f};

  // Q A-frag (K=16, quads 2,3 zero)
  const unsigned short* qrow = dq + QS_US + (size_t)bh * 16384 + (m0 + il) * 16;
  v8s qa = *(const v8s*)(qrow + (q & 1) * 8);
  qa = (q < 2) ? qa : z8;

  // PW / PH tables via MFMA
#pragma unroll
  for (int nt = 0; nt < 4; ++nt) {
    int c = nt * 16 + il;
    v8s bw = *(const v8s*)(krwb + c * 16 + (q & 1) * 8);
    v8s bhh = *(const v8s*)(krhb + c * 16 + (q & 1) * 8);
    bw = (q < 2) ? bw : z8;
    bhh = (q < 2) ? bhh : z8;
    v4f pwc = __builtin_amdgcn_mfma_f32_16x16x32_bf16(qa, bw, z4, 0, 0, 0);
    v4f phc = __builtin_amdgcn_mfma_f32_16x16x32_bf16(qa, bhh, z4, 0, 0, 0);
#pragma unroll
    for (int r = 0; r < 4; ++r) {
      pw[(q * 4 + r) * 63 + c] = pwc[r];
      ph[(q * 4 + r) * 68 + c] = phc[r] - SHIFT2;
    }
  }

  v4f oacc = z4;
  float ssum[4] = {0.f, 0.f, 0.f, 0.f};
  const unsigned short* kbase = dq + KS_US + (size_t)bh * 16384;
  const unsigned short* vbase = dq + VTS_US + (size_t)bh * 16384;
  int ibase = il + 31 - mxb - q * 4;

  for (int ny = 0; ny < 32; ++ny) {
    int idxh = ny - my + 31;
    float phr[4];
#pragma unroll
    for (int r = 0; r < 4; ++r) phr[r] = ph[(q * 4 + r) * 68 + idxh];
#pragma unroll
    for (int nt2 = 0; nt2 < 2; ++nt2) {
      int nb = ny * 32 + nt2 * 16;
      v8s kb = *(const v8s*)(kbase + (nb + il) * 16 + (q & 1) * 8);
      kb = (q < 2) ? kb : z8;
      v4f s = __builtin_amdgcn_mfma_f32_16x16x32_bf16(qa, kb, z4, 0, 0, 0);
#pragma unroll
      for (int r = 0; r < 4; ++r) {
        float pwv = pw[(q * 4 + r) * 63 + (ibase + nt2 * 16 - r)];
        float t = s[r] + pwv + phr[r];
        float p = exp2f(t);
        ssum[r] += p;
        pl[(q * 4 + r) * 36 + nt2 * 16 + il] = p;
      }
    }
    float4 pa0 = *(const float4*)(pl + il * 36 + q * 8);
    float4 pa1 = *(const float4*)(pl + il * 36 + q * 8 + 4);
    v8s pf;
    pf[0] = (short)f2bs(pa0.x); pf[1] = (short)f2bs(pa0.y);
    pf[2] = (short)f2bs(pa0.z); pf[3] = (short)f2bs(pa0.w);
    pf[4] = (short)f2bs(pa1.x); pf[5] = (short)f2bs(pa1.y);
    pf[6] = (short)f2bs(pa1.z); pf[7] = (short)f2bs(pa1.w);
    v8s vb = *(const v8s*)(vbase + (ny * 16 + il) * 32 + q * 8);
    oacc = __builtin_amdgcn_mfma_f32_16x16x32_bf16(pf, vb, oacc, 0, 0, 0);
  }

#pragma unroll
  for (int r = 0; r < 4; ++r) {
    float s = ssum[r];
    s += __shfl_xor(s, 1); s += __shfl_xor(s, 2);
    s += __shfl_xor(s, 4); s += __shfl_xor(s, 8);
    ssum[r] = s;
  }
  unsigned short* abase = (b < 6) ? (dq + ART1_US + (size_t)b * 131072)
                                  : (wsart + (size_t)(b - 6) * 131072);
#pragma unroll
  for (int r = 0; r < 4; ++r) {
    int m = m0 + q * 4 + r;
    int c = h * 16 + (m >> 6);                // ci of art
    int pp = (m & 63) * 16 + il;              // pos' of art
    abase[((c >> 5) * 1024 + pp) * 32 + (c & 31)] = f2bs(oacc[r] / ssum[r]);
  }
}

// ---------------------------------------------------------------------------
// attn_out GEMM: A from artX (contiguous), B from WA2 (frag-major).
__global__ __launch_bounds__(64) void attn_out_mfma(
    const unsigned short* __restrict__ dq, const unsigned short* __restrict__ wsart,
    const unsigned short* __restrict__ wa2, const float* __restrict__ ba,
    float* __restrict__ out) {
  int lane = threadIdx.x; int il = lane & 15, q = lane >> 4;
  int m0 = blockIdx.x * 64, coG = blockIdx.y;
  int b = m0 >> 10, pp0 = m0 & 1023;
  const unsigned short* ab = (b < 6) ? (dq + ART1_US + (size_t)b * 131072)
                                     : (wsart + (size_t)(b - 6) * 131072);
  const unsigned short* bt = wa2 + (size_t)coG * 8192 + lane * 8;
  v4f acc[4][4];
#pragma unroll
  for (int mt = 0; mt < 4; ++mt)
#pragma unroll
    for (int nt = 0; nt < 4; ++nt) acc[mt][nt] = (v4f){0.f, 0.f, 0.f, 0.f};
#pragma unroll
  for (int kc = 0; kc < 4; ++kc) {
    v8s af[4], bf[4];
#pragma unroll
    for (int nt = 0; nt < 4; ++nt)
      bf[nt] = *(const v8s*)(bt + (nt * 4 + kc) * 512);
#pragma unroll
    for (int mt = 0; mt < 4; ++mt)
      af[mt] = *(const v8s*)(ab + (kc * 1024 + pp0 + mt * 16 + il) * 32 + q * 8);
#pragma unroll
    for (int mt = 0; mt < 4; ++mt)
#pragma unroll
      for (int nt = 0; nt < 4; ++nt)
        acc[mt][nt] = __builtin_amdgcn_mfma_f32_16x16x32_bf16(
            af[mt], bf[nt], acc[mt][nt], 0, 0, 0);
  }
  int co0 = coG * 64;
#pragma unroll
  for (int nt = 0; nt < 4; ++nt) {
    int co = co0 + nt * 16 + il;
    float bias = ba[co];
#pragma unroll
    for (int mt = 0; mt < 4; ++mt) {
      v4f a = acc[mt][nt];
      float4 v; v.x = a[0] + bias; v.y = a[1] + bias;
      v.z = a[2] + bias; v.w = a[3] + bias;
      *(float4*)(out + ((size_t)(b * 512 + 384 + co)) * 1024 + pp0 + mt * 16 + q * 4) = v;
    }
  }
}

// ---------------------------------------------------------------------------
// conv3x3 via MFMA on XC: every A/B frag load is contiguous 1KB.
__global__ __launch_bounds__(64) void conv_mfma(
    const unsigned short* __restrict__ xc, const unsigned short* __restrict__ wb2,
    const float* __restrict__ bo, float* __restrict__ out) {
  int lane = threadIdx.x; int il = lane & 15, q = lane >> 4;
  int pt = blockIdx.x, coG = blockIdx.y, b = blockIdx.z;
  int pos0 = pt * 64;
  int row0 = pos0 >> 5;
  v4f acc[4][4];
#pragma unroll
  for (int mt = 0; mt < 4; ++mt)
#pragma unroll
    for (int nt = 0; nt < 4; ++nt) acc[mt][nt] = (v4f){0.f, 0.f, 0.f, 0.f};

#pragma unroll
  for (int ky = 0; ky < 3; ++ky) {
#pragma unroll
    for (int kx = 0; kx < 3; ++kx) {
      const unsigned short* bt =
          wb2 + (size_t)((ky * 3 + kx) * 6 + coG) * 16384 + lane * 8;
      int pix[4];
#pragma unroll
      for (int mt = 0; mt < 4; ++mt)
        pix[mt] = (row0 + (mt >> 1) + ky) * 34 + ((mt & 1) * 16 + il + kx);
#pragma unroll 2
      for (int kc = 0; kc < 8; ++kc) {
        v8s bf[4], af[4];
#pragma unroll
        for (int nt = 0; nt < 4; ++nt)
          bf[nt] = *(const v8s*)(bt + (nt * 8 + kc) * 512);
#pragma unroll
        for (int mt = 0; mt < 4; ++mt)
          af[mt] = *(const v8s*)(xc + ((size_t)(b * 8 + kc) * 1156 + pix[mt]) * 32 + q * 8);
#pragma unroll
        for (int mt = 0; mt < 4; ++mt)
#pragma unroll
          for (int nt = 0; nt < 4; ++nt)
            acc[mt][nt] = __builtin_amdgcn_mfma_f32_16x16x32_bf16(
                af[mt], bf[nt], acc[mt][nt], 0, 0, 0);
      }
    }
  }
  int co0 = coG * 64;
#pragma unroll
  for (int nt = 0; nt < 4; ++nt) {
    int co = co0 + nt * 16 + il;
    float bias = bo[co];
#pragma unroll
    for (int mt = 0; mt < 4; ++mt) {
      v4f a = acc[mt][nt];
      float4 v; v.x = a[0] + bias; v.y = a[1] + bias;
      v.z = a[2] + bias; v.w = a[3] + bias;
      *(float4*)(out + ((size_t)(b * 512 + co)) * 1024 + pos0 + mt * 16 + q * 4) = v;
    }
  }
}

// ---------------------------------------------------------------------------
extern "C" void kernel_launch(void* const* d_in, const int* in_sizes, int n_in,
                              void* d_out, int out_size, void* d_ws, size_t ws_size,
                              hipStream_t stream) {
  const float* x      = (const float*)d_in[0];
  const float* b_out  = (const float*)d_in[2];
  const float* b_kqv  = (const float*)d_in[4];
  const float* b_attn = (const float*)d_in[6];
  const float* krw    = (const float*)d_in[7];
  const float* krh    = (const float*)d_in[8];
  unsigned short* ws = (unsigned short*)d_ws;
  float* out = (float*)d_out;
  unsigned short* dq = (unsigned short*)d_out;

  prep_kernel<<<3912, 256, 0, stream>>>(
      (const float*)d_in[1], (const float*)d_in[3], (const float*)d_in[5],
      krw, krh, ws);
  zero_xc_kernel<<<1156, 256, 0, stream>>>(ws + XC_US);
  xt_kernel<<<dim3(16, 4, 8), 256, 0, stream>>>(x, ws + XC_US);
  kqv_mfma<<<dim3(128, 6), 64, 0, stream>>>(
      ws + XC_US, ws + WK2_US, b_kqv, dq);
  attn_mfma<<<dim3(16, 64), 256, 0, stream>>>(
      dq, ws + KRWB_US, ws + KRHB_US, ws + ART2_US);
  attn_out_mfma<<<dim3(128, 2), 64, 0, stream>>>(
      dq, ws + ART2_US, ws + WA2_US, b_attn, out);
  conv_mfma<<<dim3(16, 6, 8), 64, 0, stream>>>(
      ws + XC_US, ws + WB2_US, b_out, out);
}

// Round 9
// 183.069 us; speedup vs baseline: 10.1407x; 1.0339x over previous
//
#include <hip/hip_runtime.h>
#include <hip/hip_bf16.h>

// ---------------------------------------------------------------------------
// SelfAttention2d, fully-MFMA pipeline, fragment-major memory layouts.
// MFMA 16x16x32 bf16: A[m=il][k=q*8+j], B[col=il][k=q*8+j], C[row=q*4+r][col=il]
//
// Attention computes S TRANSPOSED (A=K, B=Q) so each lane holds
// S[m=m0+il][n=nb+q*4+r]:  pw lookups become ny-invariant registers, ph is one
// read/ny, and P needs only an 8B LDS write + b128 read to become the PV
// A-operand (full K=32).
//
// Layouts:
//   XC   [b][kc 0..7][y 0..33][x 0..33][ci 32]  zero-padded image, bf16
//   WB2  [t9][coG6][nt4][kc8][lane64][8]        w_out frag-major
//   WK2  [coG6][nt4][kc8][lane64][8]            w_kqv frag-major
//   WA2  [coG2][nt4][kc4][lane64][8]            w_attn frag-major
//   VT   [bh][ny32][d16][ci 32]                 V^T frag-major
//   artX [b][kc4][pp1024][ci32]                 attn out, frag-major
//
// ws (ushort units, 7,262,208 B <= proven-safe 8,192,000):
//   WB2 0 / WK2 884736 / WA2 983040 / KRWB 999424 / KRHB 1000448 /
//   XC 1001472 (2,367,488) / ART2 3368960 (b=6,7 slots)
// d_out scratch (ushort): KS 0 / QS 1048576 / VT 2097152 / ART1 7340032 (b0..5)
// Order: prep -> zero_xc -> xt -> kqv -> attn -> attn_out -> conv
// ---------------------------------------------------------------------------

typedef short v8s __attribute__((ext_vector_type(8)));
typedef float v4f __attribute__((ext_vector_type(4)));

#define WB2_US   0u
#define WK2_US   884736u
#define WA2_US   983040u
#define KRWB_US  999424u
#define KRHB_US  1000448u
#define XC_US    1001472u
#define ART2_US  3368960u

#define KS_US    0u
#define QS_US    1048576u
#define VTS_US   2097152u
#define ART1_US  7340032u

#define QSCALE 0.360673760f   // 0.25 * log2(e)
#define SHIFT2 17.3123405f    // 12 * log2(e)

__device__ __forceinline__ unsigned short f2bs(float f) {
  __hip_bfloat16 h = __float2bfloat16(f);
  return *reinterpret_cast<unsigned short*>(&h);
}

// ---------------------------------------------------------------------------
__global__ __launch_bounds__(256) void prep_kernel(
    const float* __restrict__ w_out, const float* __restrict__ w_kqv,
    const float* __restrict__ w_attn, const float* __restrict__ krw,
    const float* __restrict__ krh, unsigned short* __restrict__ ws) {
  int i = blockIdx.x * 256 + threadIdx.x;
  if (i < 884736) {              // WB2[t][coG][nt][kc][lane][8]
    int j = i & 7, l = (i >> 3) & 63, kc = (i >> 9) & 7, nt = (i >> 12) & 3;
    int r = i >> 14; int coG = r % 6, t = r / 6;
    int co = coG * 64 + nt * 16 + (l & 15);
    int ci = kc * 32 + (l >> 4) * 8 + j;
    ws[WB2_US + i] = f2bs(w_out[(size_t)co * 2304 + ci * 9 + t]);
  } else if (i < 983040) {       // WK2[coG][nt][kc][lane][8]
    int o = i - 884736;
    int j = o & 7, l = (o >> 3) & 63, kc = (o >> 9) & 7, nt = (o >> 12) & 3;
    int coG = o >> 14;
    int co = coG * 64 + nt * 16 + (l & 15);
    int ci = kc * 32 + (l >> 4) * 8 + j;
    ws[WK2_US + o] = f2bs(w_kqv[co * 256 + ci]);
  } else if (i < 999424) {       // WA2[coG][nt][kc][lane][8]
    int o = i - 983040;
    int j = o & 7, l = (o >> 3) & 63, kc = (o >> 9) & 3, nt = (o >> 11) & 3;
    int coG = o >> 13;
    int co = coG * 64 + nt * 16 + (l & 15);
    int ci = kc * 32 + (l >> 4) * 8 + j;
    ws[WA2_US + o] = f2bs(w_attn[co * 128 + ci]);
  } else if (i < 1000448) {      // krw bf16 [64][16], row 63 zero
    int j = i - 999424; int c = j >> 4, d = j & 15;
    ws[KRWB_US + j] = (c < 63) ? f2bs(krw[c * 16 + d]) : (unsigned short)0;
  } else if (i < 1001472) {
    int j = i - 1000448; int c = j >> 4, d = j & 15;
    ws[KRHB_US + j] = (c < 63) ? f2bs(krh[c * 16 + d]) : (unsigned short)0;
  }
}

// ---------------------------------------------------------------------------
__global__ __launch_bounds__(256) void zero_xc_kernel(unsigned short* __restrict__ xc) {
  int i = blockIdx.x * 256 + threadIdx.x;   // 295,936 uint4 = 2,367,488 us
  uint4 z = {0u, 0u, 0u, 0u};
  ((uint4*)xc)[i] = z;
}

// ---------------------------------------------------------------------------
// x [b][ci][pos] fp32 -> XC[b][ci>>5][y+1][x+1][ci&31] bf16 via LDS tile.
__global__ __launch_bounds__(256) void xt_kernel(
    const float* __restrict__ x, unsigned short* __restrict__ xc) {
  __shared__ float t[64][65];
  int tid = threadIdx.x; int pl = tid & 63, cg = tid >> 6;
  int pos0 = blockIdx.x * 64, ci0 = blockIdx.y * 64, b = blockIdx.z;
  const float* xb = x + ((size_t)(b * 256 + ci0)) * 1024 + pos0;
#pragma unroll
  for (int i = 0; i < 16; ++i) {
    int ci_l = cg * 16 + i;
    t[ci_l][pl] = xb[(size_t)ci_l * 1024 + pl];
  }
  __syncthreads();
#pragma unroll
  for (int i = 0; i < 16; ++i) {
    int pos_l = cg * 16 + i;
    int pos = pos0 + pos_l;
    int y = (pos >> 5) + 1, xx = (pos & 31) + 1;
    int ci = ci0 + pl;
    xc[((size_t)((b * 8 + (ci >> 5)) * 34 + y) * 34 + xx) * 32 + (ci & 31)] =
        f2bs(t[pl][pos_l]);
  }
}

// ---------------------------------------------------------------------------
// kqv GEMM: A-frags from XC (tap 1,1; contiguous 1KB loads), B from WK2.
__global__ __launch_bounds__(64) void kqv_mfma(
    const unsigned short* __restrict__ xc, const unsigned short* __restrict__ wk2,
    const float* __restrict__ bkqv, unsigned short* __restrict__ dq) {
  int lane = threadIdx.x; int il = lane & 15, q = lane >> 4;
  int m0 = blockIdx.x * 64, coG = blockIdx.y;
  int b = m0 >> 10, pos0 = m0 & 1023;
  int row0 = pos0 >> 5;
  v4f acc[4][4];
#pragma unroll
  for (int mt = 0; mt < 4; ++mt)
#pragma unroll
    for (int nt = 0; nt < 4; ++nt) acc[mt][nt] = (v4f){0.f, 0.f, 0.f, 0.f};

  int pix[4];
#pragma unroll
  for (int mt = 0; mt < 4; ++mt)
    pix[mt] = (row0 + (mt >> 1) + 1) * 34 + ((mt & 1) * 16 + il + 1);
  const unsigned short* bt = wk2 + (size_t)coG * 16384 + lane * 8;

#pragma unroll 2
  for (int kc = 0; kc < 8; ++kc) {
    v8s af[4], bf[4];
#pragma unroll
    for (int nt = 0; nt < 4; ++nt)
      bf[nt] = *(const v8s*)(bt + (nt * 8 + kc) * 512);
#pragma unroll
    for (int mt = 0; mt < 4; ++mt)
      af[mt] = *(const v8s*)(xc + ((size_t)(b * 8 + kc) * 1156 + pix[mt]) * 32 + q * 8);
#pragma unroll
    for (int mt = 0; mt < 4; ++mt)
#pragma unroll
      for (int nt = 0; nt < 4; ++nt)
        acc[mt][nt] = __builtin_amdgcn_mfma_f32_16x16x32_bf16(
            af[mt], bf[nt], acc[mt][nt], 0, 0, 0);
  }
  int co0 = coG * 64;
#pragma unroll
  for (int nt = 0; nt < 4; ++nt) {
    int cob = co0 + nt * 16;
    int co = cob + il;
    float bias = bkqv[co];
    int cls = cob >> 7;                  // 0:k 1:q 2:v (uniform per nt)
    int h = (cob >> 4) & 7;
    size_t bh = (size_t)(b * 8 + h);
#pragma unroll
    for (int mt = 0; mt < 4; ++mt) {
      int pos = pos0 + mt * 16 + q * 4;
      v4f a = acc[mt][nt];
#pragma unroll
      for (int r = 0; r < 4; ++r) {
        float v = a[r] + bias;
        int p = pos + r;
        if (cls == 0)      dq[KS_US + bh * 16384 + p * 16 + il] = f2bs(v);
        else if (cls == 1) dq[QS_US + bh * 16384 + p * 16 + il] = f2bs(v * QSCALE);
        else               dq[VTS_US + bh * 16384 + ((p >> 5) * 16 + il) * 32 + (p & 31)] = f2bs(v);
      }
    }
  }
}

// ---------------------------------------------------------------------------
// MFMA attention, S-transposed formulation. Block 256 = 4 waves; wave owns a
// 16-row m-tile. Lane (q,il) reg r holds S[m0+il][nb+q*4+r].
__global__ __launch_bounds__(256) void attn_mfma(
    unsigned short* __restrict__ dq, const unsigned short* __restrict__ krwb,
    const unsigned short* __restrict__ krhb, unsigned short* __restrict__ wsart) {
  __shared__ float lds[4][2448];
  int tid = threadIdx.x; int w = tid >> 6, lane = tid & 63;
  int il = lane & 15, q = lane >> 4;
  int bh = blockIdx.y; int b = bh >> 3, h = bh & 7;
  int m0 = blockIdx.x * 64 + w * 16;
  int my = m0 >> 5, mxb = m0 & 31;
  float* pw = lds[w];                       // [16 rows][stride 64]
  float* ph = pw + 1024;                    // [16 rows][stride 68], - SHIFT2
  unsigned short* pl = (unsigned short*)(ph + 1088);  // [16 rows][stride 40] bf16

  const v8s z8 = {0, 0, 0, 0, 0, 0, 0, 0};
  const v4f z4 = {0.f, 0.f, 0.f, 0.f};

  // Q frag: A-layout for table build == B-layout for S^T (same registers).
  const unsigned short* qrow = dq + QS_US + (size_t)bh * 16384 + (m0 + il) * 16;
  v8s qa = *(const v8s*)(qrow + (q & 1) * 8);
  qa = (q < 2) ? qa : z8;

  // PW / PH tables via MFMA (C row = m-row in tile, col = table col)
#pragma unroll
  for (int nt = 0; nt < 4; ++nt) {
    int c = nt * 16 + il;
    v8s bw = *(const v8s*)(krwb + c * 16 + (q & 1) * 8);
    v8s bhh = *(const v8s*)(krhb + c * 16 + (q & 1) * 8);
    bw = (q < 2) ? bw : z8;
    bhh = (q < 2) ? bhh : z8;
    v4f pwc = __builtin_amdgcn_mfma_f32_16x16x32_bf16(qa, bw, z4, 0, 0, 0);
    v4f phc = __builtin_amdgcn_mfma_f32_16x16x32_bf16(qa, bhh, z4, 0, 0, 0);
#pragma unroll
    for (int r = 0; r < 4; ++r) {
      pw[(q * 4 + r) * 64 + c] = pwc[r];
      ph[(q * 4 + r) * 68 + c] = phc[r] - SHIFT2;
    }
  }
  __builtin_amdgcn_wave_barrier();

  // pw lookups are ny-invariant per lane in the transposed scheme: hoist.
  float pwv[2][4];
#pragma unroll
  for (int nt2 = 0; nt2 < 2; ++nt2)
#pragma unroll
    for (int r = 0; r < 4; ++r)
      pwv[nt2][r] = pw[il * 64 + (nt2 * 16 + q * 4 + r) - mxb - il + 31];

  v4f oacc = z4;
  float sacc = 0.f;
  const unsigned short* kbase = dq + KS_US + (size_t)bh * 16384;
  const unsigned short* vbase = dq + VTS_US + (size_t)bh * 16384;

  for (int ny = 0; ny < 32; ++ny) {
    float phv = ph[il * 68 + (ny - my + 31)];
    v4f s[2];
#pragma unroll
    for (int nt2 = 0; nt2 < 2; ++nt2) {
      v8s kb = *(const v8s*)(kbase + (ny * 32 + nt2 * 16 + il) * 16 + (q & 1) * 8);
      kb = (q < 2) ? kb : z8;
      s[nt2] = __builtin_amdgcn_mfma_f32_16x16x32_bf16(kb, qa, z4, 0, 0, 0);
    }
#pragma unroll
    for (int nt2 = 0; nt2 < 2; ++nt2) {
      float p[4];
#pragma unroll
      for (int r = 0; r < 4; ++r) {
        float t = s[nt2][r] + pwv[nt2][r] + phv;
        p[r] = exp2f(t);
        sacc += p[r];
      }
      uint2 pk;
      pk.x = (unsigned)f2bs(p[0]) | ((unsigned)f2bs(p[1]) << 16);
      pk.y = (unsigned)f2bs(p[2]) | ((unsigned)f2bs(p[3]) << 16);
      *(uint2*)(pl + il * 40 + nt2 * 16 + q * 4) = pk;
    }
    __builtin_amdgcn_wave_barrier();
    v8s pf = *(const v8s*)(pl + il * 40 + q * 8);
    v8s vb = *(const v8s*)(vbase + (ny * 16 + il) * 32 + q * 8);
    oacc = __builtin_amdgcn_mfma_f32_16x16x32_bf16(pf, vb, oacc, 0, 0, 0);
    __builtin_amdgcn_wave_barrier();
  }

  // row sums: lane holds partial for row il; combine quads, then fetch per-r.
  sacc += __shfl_xor(sacc, 16);
  sacc += __shfl_xor(sacc, 32);

  unsigned short* abase = (b < 6) ? (dq + ART1_US + (size_t)b * 131072)
                                  : (wsart + (size_t)(b - 6) * 131072);
#pragma unroll
  for (int r = 0; r < 4; ++r) {
    float sr = __shfl(sacc, q * 4 + r);       // full sum for row q*4+r
    int m = m0 + q * 4 + r;
    int c = h * 16 + (m >> 6);                // ci of art
    int pp = (m & 63) * 16 + il;              // pos' of art
    abase[((c >> 5) * 1024 + pp) * 32 + (c & 31)] = f2bs(oacc[r] / sr);
  }
}

// ---------------------------------------------------------------------------
// attn_out GEMM: A from artX (contiguous), B from WA2 (frag-major).
__global__ __launch_bounds__(64) void attn_out_mfma(
    const unsigned short* __restrict__ dq, const unsigned short* __restrict__ wsart,
    const unsigned short* __restrict__ wa2, const float* __restrict__ ba,
    float* __restrict__ out) {
  int lane = threadIdx.x; int il = lane & 15, q = lane >> 4;
  int m0 = blockIdx.x * 64, coG = blockIdx.y;
  int b = m0 >> 10, pp0 = m0 & 1023;
  const unsigned short* ab = (b < 6) ? (dq + ART1_US + (size_t)b * 131072)
                                     : (wsart + (size_t)(b - 6) * 131072);
  const unsigned short* bt = wa2 + (size_t)coG * 8192 + lane * 8;
  v4f acc[4][4];
#pragma unroll
  for (int mt = 0; mt < 4; ++mt)
#pragma unroll
    for (int nt = 0; nt < 4; ++nt) acc[mt][nt] = (v4f){0.f, 0.f, 0.f, 0.f};
#pragma unroll
  for (int kc = 0; kc < 4; ++kc) {
    v8s af[4], bf[4];
#pragma unroll
    for (int nt = 0; nt < 4; ++nt)
      bf[nt] = *(const v8s*)(bt + (nt * 4 + kc) * 512);
#pragma unroll
    for (int mt = 0; mt < 4; ++mt)
      af[mt] = *(const v8s*)(ab + (kc * 1024 + pp0 + mt * 16 + il) * 32 + q * 8);
#pragma unroll
    for (int mt = 0; mt < 4; ++mt)
#pragma unroll
      for (int nt = 0; nt < 4; ++nt)
        acc[mt][nt] = __builtin_amdgcn_mfma_f32_16x16x32_bf16(
            af[mt], bf[nt], acc[mt][nt], 0, 0, 0);
  }
  int co0 = coG * 64;
#pragma unroll
  for (int nt = 0; nt < 4; ++nt) {
    int co = co0 + nt * 16 + il;
    float bias = ba[co];
#pragma unroll
    for (int mt = 0; mt < 4; ++mt) {
      v4f a = acc[mt][nt];
      float4 v; v.x = a[0] + bias; v.y = a[1] + bias;
      v.z = a[2] + bias; v.w = a[3] + bias;
      *(float4*)(out + ((size_t)(b * 512 + 384 + co)) * 1024 + pp0 + mt * 16 + q * 4) = v;
    }
  }
}

// ---------------------------------------------------------------------------
// conv3x3 via MFMA on XC: every A/B frag load is contiguous 1KB.
__global__ __launch_bounds__(64) void conv_mfma(
    const unsigned short* __restrict__ xc, const unsigned short* __restrict__ wb2,
    const float* __restrict__ bo, float* __restrict__ out) {
  int lane = threadIdx.x; int il = lane & 15, q = lane >> 4;
  int pt = blockIdx.x, coG = blockIdx.y, b = blockIdx.z;
  int pos0 = pt * 64;
  int row0 = pos0 >> 5;
  v4f acc[4][4];
#pragma unroll
  for (int mt = 0; mt < 4; ++mt)
#pragma unroll
    for (int nt = 0; nt < 4; ++nt) acc[mt][nt] = (v4f){0.f, 0.f, 0.f, 0.f};

#pragma unroll
  for (int ky = 0; ky < 3; ++ky) {
#pragma unroll
    for (int kx = 0; kx < 3; ++kx) {
      const unsigned short* bt =
          wb2 + (size_t)((ky * 3 + kx) * 6 + coG) * 16384 + lane * 8;
      int pix[4];
#pragma unroll
      for (int mt = 0; mt < 4; ++mt)
        pix[mt] = (row0 + (mt >> 1) + ky) * 34 + ((mt & 1) * 16 + il + kx);
#pragma unroll 2
      for (int kc = 0; kc < 8; ++kc) {
        v8s bf[4], af[4];
#pragma unroll
        for (int nt = 0; nt < 4; ++nt)
          bf[nt] = *(const v8s*)(bt + (nt * 8 + kc) * 512);
#pragma unroll
        for (int mt = 0; mt < 4; ++mt)
          af[mt] = *(const v8s*)(xc + ((size_t)(b * 8 + kc) * 1156 + pix[mt]) * 32 + q * 8);
#pragma unroll
        for (int mt = 0; mt < 4; ++mt)
#pragma unroll
          for (int nt = 0; nt < 4; ++nt)
            acc[mt][nt] = __builtin_amdgcn_mfma_f32_16x16x32_bf16(
                af[mt], bf[nt], acc[mt][nt], 0, 0, 0);
      }
    }
  }
  int co0 = coG * 64;
#pragma unroll
  for (int nt = 0; nt < 4; ++nt) {
    int co = co0 + nt * 16 + il;
    float bias = bo[co];
#pragma unroll
    for (int mt = 0; mt < 4; ++mt) {
      v4f a = acc[mt][nt];
      float4 v; v.x = a[0] + bias; v.y = a[1] + bias;
      v.z = a[2] + bias; v.w = a[3] + bias;
      *(float4*)(out + ((size_t)(b * 512 + co)) * 1024 + pos0 + mt * 16 + q * 4) = v;
    }
  }
}

// ---------------------------------------------------------------------------
extern "C" void kernel_launch(void* const* d_in, const int* in_sizes, int n_in,
                              void* d_out, int out_size, void* d_ws, size_t ws_size,
                              hipStream_t stream) {
  const float* x      = (const float*)d_in[0];
  const float* b_out  = (const float*)d_in[2];
  const float* b_kqv  = (const float*)d_in[4];
  const float* b_attn = (const float*)d_in[6];
  const float* krw    = (const float*)d_in[7];
  const float* krh    = (const float*)d_in[8];
  unsigned short* ws = (unsigned short*)d_ws;
  float* out = (float*)d_out;
  unsigned short* dq = (unsigned short*)d_out;

  prep_kernel<<<3912, 256, 0, stream>>>(
      (const float*)d_in[1], (const float*)d_in[3], (const float*)d_in[5],
      krw, krh, ws);
  zero_xc_kernel<<<1156, 256, 0, stream>>>(ws + XC_US);
  xt_kernel<<<dim3(16, 4, 8), 256, 0, stream>>>(x, ws + XC_US);
  kqv_mfma<<<dim3(128, 6), 64, 0, stream>>>(
      ws + XC_US, ws + WK2_US, b_kqv, dq);
  attn_mfma<<<dim3(16, 64), 256, 0, stream>>>(
      dq, ws + KRWB_US, ws + KRHB_US, ws + ART2_US);
  attn_out_mfma<<<dim3(128, 2), 64, 0, stream>>>(
      dq, ws + ART2_US, ws + WA2_US, b_attn, out);
  conv_mfma<<<dim3(16, 6, 8), 64, 0, stream>>>(
      ws + XC_US, ws + WB2_US, b_out, out);
}